// Round 2
// baseline (720.618 us; speedup 1.0000x reference)
//
#include <hip/hip_runtime.h>
#include <stdint.h>

typedef __bf16 bf16x8  __attribute__((ext_vector_type(8)));
typedef float  f32x4   __attribute__((ext_vector_type(4)));

#define LOG2E    1.44269504088896340736f
#define SM_SCALE 0.03125f   /* 1/sqrt(1024) */

__device__ __forceinline__ uint32_t f2bf(float f) {
  uint32_t u = __builtin_bit_cast(uint32_t, f);
  u += 0x7FFFu + ((u >> 16) & 1u);   // RNE
  return u >> 16;
}
__device__ __forceinline__ uint32_t pk2(float a, float b) {
  return f2bf(a) | (f2bf(b) << 16);
}
__device__ __forceinline__ uint4 pack8(float4 a, float4 b) {
  uint4 r;
  r.x = pk2(a.x, a.y); r.y = pk2(a.z, a.w);
  r.z = pk2(b.x, b.y); r.w = pk2(b.z, b.w);
  return r;
}

struct alignas(16) LdsT {
  char  kv[2][64 * 144];   // K chunk (dbuf): 64 regions x 144B ([4key][16d] subtile + pad)
  char  qc[2][64 * 128];   // Q chunk [64 q][64 d] bf16, row XOR-swizzle ((q&7)<<4)
  char  pl[64 * 128];      // P [64 q][64 k] bf16, row XOR-swizzle
  float red[4][64];        // cross-wave reduce scratch
  float mrow[64];          // running max (logit units)
  float lrow[64];          // running denom
  float fac[64];           // rescale factor per kstep
};

// ---------------- prepass: build V^T bf16 [prob][1024 d][512 key] in ws ----------------
__global__ __launch_bounds__(256)
void vt_prepass(const float* __restrict__ x, uint16_t* __restrict__ vt) {
  __shared__ char tl[64 * 144];
  const int t    = threadIdx.x;
  const int blk  = blockIdx.x;
  const int dc   = blk & 15;          // 64-d chunk
  const int kb   = (blk >> 4) & 7;    // 64-key chunk
  const int prob = blk >> 7;          // 0..63
  const int b  = prob >> 4, off = (prob >> 2) & 3, gs = prob & 3;

  const int key = t >> 2, dq = t & 3;
  const float* src = x + ((size_t)(b * 8192 + gs * 2048 + (kb * 64 + key) * 4 + off)) * 1024
                     + dc * 64 + dq * 16;
  float4 f0 = *(const float4*)(src);
  float4 f1 = *(const float4*)(src + 4);
  float4 f2 = *(const float4*)(src + 8);
  float4 f3 = *(const float4*)(src + 12);
  const int swz = (key & 7) << 4;
  *(uint4*)(tl + key * 144 + ((dq * 32) ^ swz))      = pack8(f0, f1);
  *(uint4*)(tl + key * 144 + ((dq * 32 + 16) ^ swz)) = pack8(f2, f3);
  __syncthreads();
  const int d = t >> 2, kq = t & 3;
  uint32_t w[8];
#pragma unroll
  for (int i = 0; i < 8; ++i) {
    int k0 = kq * 16 + 2 * i, k1 = k0 + 1;
    uint32_t a  = *(const uint16_t*)(tl + k0 * 144 + ((2 * d) ^ ((k0 & 7) << 4)));
    uint32_t bb = *(const uint16_t*)(tl + k1 * 144 + ((2 * d) ^ ((k1 & 7) << 4)));
    w[i] = a | (bb << 16);
  }
  uint16_t* dst = vt + ((size_t)(prob * 1024 + dc * 64 + d)) * 512 + kb * 64 + kq * 16;
  *(uint4*)(dst)     = *(uint4*)&w[0];
  *(uint4*)(dst + 8) = *(uint4*)&w[4];
}

// ---------------- main flash kernel ----------------
template <int USE_VT>
__global__ __launch_bounds__(512, 4)
void dilattn_kernel(const float* __restrict__ x, const uint16_t* __restrict__ vt,
                    float* __restrict__ out) {
  __shared__ LdsT lds;

  const int tid  = threadIdx.x;
  const int lane = tid & 63;
  const int wid  = tid >> 6;
  const int h    = lane >> 4;        // 0..3
  const int l15  = lane & 15;

  const int blk  = blockIdx.x;
  const int prob = blk >> 3;
  const int q0   = (blk & 7) * 64;
  const int b    = prob >> 4;
  const int off  = (prob >> 2) & 3;
  const int gs   = prob & 3;

  const float* xb = x + (size_t)b * (8192u * 1024u);

  // staging coords: 8 threads per tile row, 8 floats each
  const int srow8 = tid >> 3;
  const int c8    = tid & 7;
  const float* gq_row = xb + (size_t)(gs * 2048 + (q0 + srow8) * 4 + off) * 1024 + c8 * 8;

  // QK^T wave map: key-tile ktQ, q-tiles qtA, qtA+1
  const int ktQ = wid & 3;
  const int qtA = (wid >> 2) * 2;

  // LDS offsets (QK^T phase — verified round-0 layout)
  const int akBase = (4 * ktQ + (l15 >> 2)) * 4;
  const int akSub  = (lane & 3) * 32 + (h & 1) * 16;
  const int akOff0 = (akBase + 0 + (h >> 1)) * 144 + akSub;
  const int akOff1 = (akBase + 2 + (h >> 1)) * 144 + akSub;
  const int qA = 16 * qtA + l15, qB = qA + 16;
  const int qAsw = (qA & 7) << 4, qBsw = (qB & 7) << 4;
  const int bqA0 = qA * 128 + ((16 * h +  0) ^ qAsw);
  const int bqA1 = qA * 128 + ((16 * h + 64) ^ qAsw);
  const int bqB0 = qB * 128 + ((16 * h +  0) ^ qBsw);
  const int bqB1 = qB * 128 + ((16 * h + 64) ^ qBsw);
  const int qWr = srow8 * 128 + ((c8 * 16) ^ ((srow8 & 7) << 4));
  const int kWr = ((srow8 >> 2) * 4 + (c8 >> 1)) * 144 + (srow8 & 3) * 32 + (c8 & 1) * 16;
  const int pWrA = qA * 128 + (((16 * ktQ + 4 * h) * 2) ^ qAsw);
  const int pWrB = qB * 128 + (((16 * ktQ + 4 * h) * 2) ^ qBsw);
  const int psw  = (l15 & 7) << 4;

  if (tid < 64) { lds.mrow[tid] = -1e30f; lds.lrow[tid] = 0.0f; }

  // PV: wave owns d-slice [128*wid, 128*wid+128): acc[cd][qt], cd = (c2<<2)|dt
  f32x4 acc[8][4];
#pragma unroll
  for (int i = 0; i < 8; ++i)
#pragma unroll
    for (int j = 0; j < 4; ++j) acc[i][j] = (f32x4){0.f, 0.f, 0.f, 0.f};

  for (int kb = 0; kb < 8; ++kb) {
    const float* gk_row = xb + (size_t)(gs * 2048 + (kb * 64 + srow8) * 4 + off) * 1024 + c8 * 8;

    // ================= QK^T sweep over 16 d-chunks (round-0 verified) =================
    f32x4 tA = (f32x4){0.f, 0.f, 0.f, 0.f};
    f32x4 tB = (f32x4){0.f, 0.f, 0.f, 0.f};
    {
      float4 a0 = *(const float4*)(gq_row);
      float4 a1 = *(const float4*)(gq_row + 4);
      float4 b0 = *(const float4*)(gk_row);
      float4 b1 = *(const float4*)(gk_row + 4);
      *(uint4*)(lds.qc[0] + qWr) = pack8(a0, a1);
      *(uint4*)(lds.kv[0] + kWr) = pack8(b0, b1);
    }
    __syncthreads();
#pragma unroll
    for (int c = 0; c < 16; ++c) {
      const int buf = c & 1;
      float4 nq0, nq1, nk0, nk1;
      if (c < 15) {
        const float* gq = gq_row + (c + 1) * 64;
        const float* gk = gk_row + (c + 1) * 64;
        nq0 = *(const float4*)gq; nq1 = *(const float4*)(gq + 4);
        nk0 = *(const float4*)gk; nk1 = *(const float4*)(gk + 4);
      }
      const char* kvb = lds.kv[buf];
      const char* qcb = lds.qc[buf];
      bf16x8 aK0 = *(const bf16x8*)(kvb + akOff0);
      bf16x8 aK1 = *(const bf16x8*)(kvb + akOff1);
      bf16x8 bq0 = *(const bf16x8*)(qcb + bqA0);
      bf16x8 bq1 = *(const bf16x8*)(qcb + bqB0);
      tA = __builtin_amdgcn_mfma_f32_16x16x32_bf16(aK0, bq0, tA, 0, 0, 0);
      tB = __builtin_amdgcn_mfma_f32_16x16x32_bf16(aK0, bq1, tB, 0, 0, 0);
      bq0 = *(const bf16x8*)(qcb + bqA1);
      bq1 = *(const bf16x8*)(qcb + bqB1);
      tA = __builtin_amdgcn_mfma_f32_16x16x32_bf16(aK1, bq0, tA, 0, 0, 0);
      tB = __builtin_amdgcn_mfma_f32_16x16x32_bf16(aK1, bq1, tB, 0, 0, 0);
      if (c < 15) {
        *(uint4*)(lds.qc[buf ^ 1] + qWr) = pack8(nq0, nq1);
        *(uint4*)(lds.kv[buf ^ 1] + kWr) = pack8(nk0, nk1);
      }
      __syncthreads();
    }

    // ================= online softmax =================
    float mA = fmaxf(fmaxf(tA[0], tA[1]), fmaxf(tA[2], tA[3])) * SM_SCALE;
    float mB = fmaxf(fmaxf(tB[0], tB[1]), fmaxf(tB[2], tB[3])) * SM_SCALE;
    mA = fmaxf(mA, __shfl_xor(mA, 16, 64)); mA = fmaxf(mA, __shfl_xor(mA, 32, 64));
    mB = fmaxf(mB, __shfl_xor(mB, 16, 64)); mB = fmaxf(mB, __shfl_xor(mB, 32, 64));
    if (lane < 32) lds.red[ktQ][32 * (wid >> 2) + lane] = (lane >> 4) ? mB : mA;
    __syncthreads();                                      // barrier A
    if (wid == 0) {
      float mt = fmaxf(fmaxf(lds.red[0][lane], lds.red[1][lane]),
                       fmaxf(lds.red[2][lane], lds.red[3][lane]));
      float mu = lds.mrow[lane];
      float mn = fmaxf(mu, mt);
      lds.fac[lane]  = exp2f((mu - mn) * LOG2E);
      lds.mrow[lane] = mn;
    }
    __syncthreads();                                      // barrier B
    {
      const float mnA = lds.mrow[qA];
      const float mnB = lds.mrow[qB];
      float pA0 = exp2f((tA[0] * SM_SCALE - mnA) * LOG2E);
      float pA1 = exp2f((tA[1] * SM_SCALE - mnA) * LOG2E);
      float pA2 = exp2f((tA[2] * SM_SCALE - mnA) * LOG2E);
      float pA3 = exp2f((tA[3] * SM_SCALE - mnA) * LOG2E);
      float pB0 = exp2f((tB[0] * SM_SCALE - mnB) * LOG2E);
      float pB1 = exp2f((tB[1] * SM_SCALE - mnB) * LOG2E);
      float pB2 = exp2f((tB[2] * SM_SCALE - mnB) * LOG2E);
      float pB3 = exp2f((tB[3] * SM_SCALE - mnB) * LOG2E);
      uint2 wA; wA.x = pk2(pA0, pA1); wA.y = pk2(pA2, pA3);
      uint2 wB; wB.x = pk2(pB0, pB1); wB.y = pk2(pB2, pB3);
      *(uint2*)(lds.pl + pWrA) = wA;
      *(uint2*)(lds.pl + pWrB) = wB;
      float sA = (pA0 + pA1) + (pA2 + pA3);
      float sB = (pB0 + pB1) + (pB2 + pB3);
      sA += __shfl_xor(sA, 16, 64); sA += __shfl_xor(sA, 32, 64);
      sB += __shfl_xor(sB, 16, 64); sB += __shfl_xor(sB, 32, 64);
      if (lane < 32) lds.red[ktQ][32 * (wid >> 2) + lane] = (lane >> 4) ? sB : sA;
      // rescale O accumulator by fac (valid since barrier B)
#pragma unroll
      for (int qt = 0; qt < 4; ++qt) {
        f32x4 fv = *(const f32x4*)&lds.fac[16 * qt + 4 * h];
#pragma unroll
        for (int cd = 0; cd < 8; ++cd) {
          acc[cd][qt][0] *= fv[0]; acc[cd][qt][1] *= fv[1];
          acc[cd][qt][2] *= fv[2]; acc[cd][qt][3] *= fv[3];
        }
      }
    }
    __syncthreads();                                      // barrier C
    if (wid == 0) {
      float s = (lds.red[0][lane] + lds.red[1][lane]) +
                (lds.red[2][lane] + lds.red[3][lane]);
      lds.lrow[lane] = lds.lrow[lane] * lds.fac[lane] + s;
    }

    // ================= PV: P in regs, V direct from global V^T =================
    bf16x8 pa[4][2];
#pragma unroll
    for (int qt = 0; qt < 4; ++qt) {
      const int base = (16 * qt + l15) * 128;
      pa[qt][0] = *(const bf16x8*)(lds.pl + base + ((16 * h) ^ psw));
      pa[qt][1] = *(const bf16x8*)(lds.pl + base + ((64 + 16 * h) ^ psw));
    }
    const uint16_t* vtW = nullptr;
    if constexpr (USE_VT)
      vtW = vt + ((size_t)(prob * 1024 + 128 * wid + l15)) * 512 + (size_t)kb * 64 + 8 * h;
#pragma unroll
    for (int cd = 0; cd < 8; ++cd) {
      bf16x8 v0, v1;
      if constexpr (USE_VT) {
        const uint16_t* vp = vtW + (size_t)((cd >> 2) * 64 + (cd & 3) * 16) * 512;
        v0 = *(const bf16x8*)(vp);
        v1 = *(const bf16x8*)(vp + 32);
      } else {
        const int d = 128 * wid + (cd >> 2) * 64 + (cd & 3) * 16 + l15;
        union { bf16x8 v; uint16_t u[8]; } a0, a1;
#pragma unroll
        for (int jj = 0; jj < 8; ++jj) {
          int key = kb * 64 + 8 * h + jj;
          a0.u[jj] = (uint16_t)f2bf(xb[(size_t)(gs * 2048 + key * 4 + off) * 1024 + d]);
          a1.u[jj] = (uint16_t)f2bf(xb[(size_t)(gs * 2048 + (key + 32) * 4 + off) * 1024 + d]);
        }
        v0 = a0.v; v1 = a1.v;
      }
#pragma unroll
      for (int qt = 0; qt < 4; ++qt) {
        acc[cd][qt] = __builtin_amdgcn_mfma_f32_16x16x32_bf16(pa[qt][0], v0, acc[cd][qt], 0, 0, 0);
        acc[cd][qt] = __builtin_amdgcn_mfma_f32_16x16x32_bf16(pa[qt][1], v1, acc[cd][qt], 0, 0, 0);
      }
    }
  }

  // ================= epilogue =================
  __syncthreads();   // PV is barrier-free: ensure wid0's last lrow update is visible
#pragma unroll
  for (int qt = 0; qt < 4; ++qt) {
    f32x4 lv = *(const f32x4*)&lds.lrow[16 * qt + 4 * h];
    f32x4 inv;
    inv[0] = 0.25f / lv[0]; inv[1] = 0.25f / lv[1];
    inv[2] = 0.25f / lv[2]; inv[3] = 0.25f / lv[3];
#pragma unroll
    for (int cd = 0; cd < 8; ++cd) {
      const int d = 128 * wid + (cd >> 2) * 64 + (cd & 3) * 16 + l15;
#pragma unroll
      for (int r = 0; r < 4; ++r) {
        const int qq = q0 + 16 * qt + 4 * h + r;
        out[((size_t)(b * 8192 + gs * 2048 + qq * 4 + off)) * 1024 + d] = acc[cd][qt][r] * inv[r];
      }
    }
  }
}

extern "C" void kernel_launch(void* const* d_in, const int* in_sizes, int n_in,
                              void* d_out, int out_size, void* d_ws, size_t ws_size,
                              hipStream_t stream) {
  const float* x = (const float*)d_in[0];
  float* out = (float*)d_out;
  (void)in_sizes; (void)n_in; (void)out_size;
  const size_t vt_bytes = 64ull * 1024 * 512 * 2;   // 67,108,864
  if (ws_size >= vt_bytes) {
    uint16_t* vt = (uint16_t*)d_ws;
    vt_prepass<<<8192, 256, 0, stream>>>(x, vt);
    dilattn_kernel<1><<<512, 512, 0, stream>>>(x, vt, out);
  } else {
    dilattn_kernel<0><<<512, 512, 0, stream>>>(x, nullptr, out);
  }
}

// Round 3
// 311.480 us; speedup vs baseline: 2.3135x; 2.3135x over previous
//
#include <hip/hip_runtime.h>
#include <stdint.h>

typedef __bf16 bf16x8  __attribute__((ext_vector_type(8)));
typedef float  f32x4   __attribute__((ext_vector_type(4)));

#define LOG2E    1.44269504088896340736f
#define SM_SCALE 0.03125f   /* 1/sqrt(1024) */

__device__ __forceinline__ uint32_t f2bf(float f) {
  uint32_t u = __builtin_bit_cast(uint32_t, f);
  u += 0x7FFFu + ((u >> 16) & 1u);   // RNE
  return u >> 16;
}
__device__ __forceinline__ uint32_t pk2(float a, float b) {
  return f2bf(a) | (f2bf(b) << 16);
}
__device__ __forceinline__ uint4 pack8(float4 a, float4 b) {
  uint4 r;
  r.x = pk2(a.x, a.y); r.y = pk2(a.z, a.w);
  r.z = pk2(b.x, b.y); r.w = pk2(b.z, b.w);
  return r;
}

struct alignas(16) LdsT {
  char  kv[2][64 * 144];   // K chunk (dbuf): 64 regions x 144B ([4key][16d] subtile + pad)
  char  qc[2][64 * 128];   // Q chunk [64 q][64 d] bf16, row XOR-swizzle ((q&7)<<4)
  char  pl[64 * 128];      // P [64 q][64 k] bf16, row XOR-swizzle
  float red[4][64];        // cross-wave reduce scratch
  float mrow[64];          // running max (logit units)
  float lrow[64];          // running denom
  float fac[64];           // rescale factor per kstep
};

// ---------------- prepass: build V^T bf16 [prob][1024 d][512 key] in ws ----------------
__global__ __launch_bounds__(256)
void vt_prepass(const float* __restrict__ x, uint16_t* __restrict__ vt) {
  __shared__ char tl[64 * 144];
  const int t    = threadIdx.x;
  const int blk  = blockIdx.x;
  const int dc   = blk & 15;          // 64-d chunk
  const int kb   = (blk >> 4) & 7;    // 64-key chunk
  const int prob = blk >> 7;          // 0..63
  const int b  = prob >> 4, off = (prob >> 2) & 3, gs = prob & 3;

  const int key = t >> 2, dq = t & 3;
  const float* src = x + ((size_t)(b * 8192 + gs * 2048 + (kb * 64 + key) * 4 + off)) * 1024
                     + dc * 64 + dq * 16;
  float4 f0 = *(const float4*)(src);
  float4 f1 = *(const float4*)(src + 4);
  float4 f2 = *(const float4*)(src + 8);
  float4 f3 = *(const float4*)(src + 12);
  const int swz = (key & 7) << 4;
  *(uint4*)(tl + key * 144 + ((dq * 32) ^ swz))      = pack8(f0, f1);
  *(uint4*)(tl + key * 144 + ((dq * 32 + 16) ^ swz)) = pack8(f2, f3);
  __syncthreads();
  const int d = t >> 2, kq = t & 3;
  uint32_t w[8];
#pragma unroll
  for (int i = 0; i < 8; ++i) {
    int k0 = kq * 16 + 2 * i, k1 = k0 + 1;
    uint32_t a  = *(const uint16_t*)(tl + k0 * 144 + ((2 * d) ^ ((k0 & 7) << 4)));
    uint32_t bb = *(const uint16_t*)(tl + k1 * 144 + ((2 * d) ^ ((k1 & 7) << 4)));
    w[i] = a | (bb << 16);
  }
  uint16_t* dst = vt + ((size_t)(prob * 1024 + dc * 64 + d)) * 512 + kb * 64 + kq * 16;
  *(uint4*)(dst)     = *(uint4*)&w[0];
  *(uint4*)(dst + 8) = *(uint4*)&w[4];
}

// ---------------- main flash kernel ----------------
template <int USE_VT>
__global__ __launch_bounds__(512, 2)   // 2 waves/EU min -> 256-VGPR budget (was 4 -> 128: spilled acc!)
void dilattn_kernel(const float* __restrict__ x, const uint16_t* __restrict__ vt,
                    float* __restrict__ out) {
  __shared__ LdsT lds;

  const int tid  = threadIdx.x;
  const int lane = tid & 63;
  const int wid  = tid >> 6;
  const int h    = lane >> 4;        // 0..3
  const int l15  = lane & 15;

  const int blk  = blockIdx.x;
  const int prob = blk >> 3;
  const int q0   = (blk & 7) * 64;
  const int b    = prob >> 4;
  const int off  = (prob >> 2) & 3;
  const int gs   = prob & 3;

  const float* xb = x + (size_t)b * (8192u * 1024u);

  // staging coords: 8 threads per tile row, 8 floats each
  const int srow8 = tid >> 3;
  const int c8    = tid & 7;
  const float* gq_row = xb + (size_t)(gs * 2048 + (q0 + srow8) * 4 + off) * 1024 + c8 * 8;

  // QK^T wave map: key-tile ktQ, q-tiles qtA, qtA+1
  const int ktQ = wid & 3;
  const int qtA = (wid >> 2) * 2;

  // LDS offsets (QK^T phase — verified layout)
  const int akBase = (4 * ktQ + (l15 >> 2)) * 4;
  const int akSub  = (lane & 3) * 32 + (h & 1) * 16;
  const int akOff0 = (akBase + 0 + (h >> 1)) * 144 + akSub;
  const int akOff1 = (akBase + 2 + (h >> 1)) * 144 + akSub;
  const int qA = 16 * qtA + l15, qB = qA + 16;
  const int qAsw = (qA & 7) << 4, qBsw = (qB & 7) << 4;
  const int bqA0 = qA * 128 + ((16 * h +  0) ^ qAsw);
  const int bqA1 = qA * 128 + ((16 * h + 64) ^ qAsw);
  const int bqB0 = qB * 128 + ((16 * h +  0) ^ qBsw);
  const int bqB1 = qB * 128 + ((16 * h + 64) ^ qBsw);
  const int qWr = srow8 * 128 + ((c8 * 16) ^ ((srow8 & 7) << 4));
  const int kWr = ((srow8 >> 2) * 4 + (c8 >> 1)) * 144 + (srow8 & 3) * 32 + (c8 & 1) * 16;
  const int pWrA = qA * 128 + (((16 * ktQ + 4 * h) * 2) ^ qAsw);
  const int pWrB = qB * 128 + (((16 * ktQ + 4 * h) * 2) ^ qBsw);
  const int psw  = (l15 & 7) << 4;

  if (tid < 64) { lds.mrow[tid] = -1e30f; lds.lrow[tid] = 0.0f; }

  // PV: wave owns d-slice [128*wid, 128*wid+128): acc[cd][qt], cd = (c2<<2)|dt
  f32x4 acc[8][4];
#pragma unroll
  for (int i = 0; i < 8; ++i)
#pragma unroll
    for (int j = 0; j < 4; ++j) acc[i][j] = (f32x4){0.f, 0.f, 0.f, 0.f};

  for (int kb = 0; kb < 8; ++kb) {
    const float* gk_row = xb + (size_t)(gs * 2048 + (kb * 64 + srow8) * 4 + off) * 1024 + c8 * 8;

    // ================= QK^T sweep over 16 d-chunks =================
    f32x4 tA = (f32x4){0.f, 0.f, 0.f, 0.f};
    f32x4 tB = (f32x4){0.f, 0.f, 0.f, 0.f};
    {
      float4 a0 = *(const float4*)(gq_row);
      float4 a1 = *(const float4*)(gq_row + 4);
      float4 b0 = *(const float4*)(gk_row);
      float4 b1 = *(const float4*)(gk_row + 4);
      *(uint4*)(lds.qc[0] + qWr) = pack8(a0, a1);
      *(uint4*)(lds.kv[0] + kWr) = pack8(b0, b1);
    }
    __syncthreads();
#pragma unroll
    for (int c = 0; c < 16; ++c) {
      const int buf = c & 1;
      float4 nq0, nq1, nk0, nk1;
      if (c < 15) {
        const float* gq = gq_row + (c + 1) * 64;
        const float* gk = gk_row + (c + 1) * 64;
        nq0 = *(const float4*)gq; nq1 = *(const float4*)(gq + 4);
        nk0 = *(const float4*)gk; nk1 = *(const float4*)(gk + 4);
      }
      const char* kvb = lds.kv[buf];
      const char* qcb = lds.qc[buf];
      bf16x8 aK0 = *(const bf16x8*)(kvb + akOff0);
      bf16x8 aK1 = *(const bf16x8*)(kvb + akOff1);
      bf16x8 bq0 = *(const bf16x8*)(qcb + bqA0);
      bf16x8 bq1 = *(const bf16x8*)(qcb + bqB0);
      tA = __builtin_amdgcn_mfma_f32_16x16x32_bf16(aK0, bq0, tA, 0, 0, 0);
      tB = __builtin_amdgcn_mfma_f32_16x16x32_bf16(aK0, bq1, tB, 0, 0, 0);
      bq0 = *(const bf16x8*)(qcb + bqA1);
      bq1 = *(const bf16x8*)(qcb + bqB1);
      tA = __builtin_amdgcn_mfma_f32_16x16x32_bf16(aK1, bq0, tA, 0, 0, 0);
      tB = __builtin_amdgcn_mfma_f32_16x16x32_bf16(aK1, bq1, tB, 0, 0, 0);
      if (c < 15) {
        *(uint4*)(lds.qc[buf ^ 1] + qWr) = pack8(nq0, nq1);
        *(uint4*)(lds.kv[buf ^ 1] + kWr) = pack8(nk0, nk1);
      }
      __syncthreads();
    }

    // ================= online softmax =================
    float mA = fmaxf(fmaxf(tA[0], tA[1]), fmaxf(tA[2], tA[3])) * SM_SCALE;
    float mB = fmaxf(fmaxf(tB[0], tB[1]), fmaxf(tB[2], tB[3])) * SM_SCALE;
    mA = fmaxf(mA, __shfl_xor(mA, 16, 64)); mA = fmaxf(mA, __shfl_xor(mA, 32, 64));
    mB = fmaxf(mB, __shfl_xor(mB, 16, 64)); mB = fmaxf(mB, __shfl_xor(mB, 32, 64));
    if (lane < 32) lds.red[ktQ][32 * (wid >> 2) + lane] = (lane >> 4) ? mB : mA;
    __syncthreads();                                      // barrier A
    if (wid == 0) {
      float mt = fmaxf(fmaxf(lds.red[0][lane], lds.red[1][lane]),
                       fmaxf(lds.red[2][lane], lds.red[3][lane]));
      float mu = lds.mrow[lane];
      float mn = fmaxf(mu, mt);
      lds.fac[lane]  = exp2f((mu - mn) * LOG2E);
      lds.mrow[lane] = mn;
    }
    __syncthreads();                                      // barrier B
    {
      const float mnA = lds.mrow[qA];
      const float mnB = lds.mrow[qB];
      float pA0 = exp2f((tA[0] * SM_SCALE - mnA) * LOG2E);
      float pA1 = exp2f((tA[1] * SM_SCALE - mnA) * LOG2E);
      float pA2 = exp2f((tA[2] * SM_SCALE - mnA) * LOG2E);
      float pA3 = exp2f((tA[3] * SM_SCALE - mnA) * LOG2E);
      float pB0 = exp2f((tB[0] * SM_SCALE - mnB) * LOG2E);
      float pB1 = exp2f((tB[1] * SM_SCALE - mnB) * LOG2E);
      float pB2 = exp2f((tB[2] * SM_SCALE - mnB) * LOG2E);
      float pB3 = exp2f((tB[3] * SM_SCALE - mnB) * LOG2E);
      uint2 wA; wA.x = pk2(pA0, pA1); wA.y = pk2(pA2, pA3);
      uint2 wB; wB.x = pk2(pB0, pB1); wB.y = pk2(pB2, pB3);
      *(uint2*)(lds.pl + pWrA) = wA;
      *(uint2*)(lds.pl + pWrB) = wB;
      float sA = (pA0 + pA1) + (pA2 + pA3);
      float sB = (pB0 + pB1) + (pB2 + pB3);
      sA += __shfl_xor(sA, 16, 64); sA += __shfl_xor(sA, 32, 64);
      sB += __shfl_xor(sB, 16, 64); sB += __shfl_xor(sB, 32, 64);
      if (lane < 32) lds.red[ktQ][32 * (wid >> 2) + lane] = (lane >> 4) ? sB : sA;
      // rescale O accumulator by fac (valid since barrier B)
#pragma unroll
      for (int qt = 0; qt < 4; ++qt) {
        f32x4 fv = *(const f32x4*)&lds.fac[16 * qt + 4 * h];
#pragma unroll
        for (int cd = 0; cd < 8; ++cd) {
          acc[cd][qt][0] *= fv[0]; acc[cd][qt][1] *= fv[1];
          acc[cd][qt][2] *= fv[2]; acc[cd][qt][3] *= fv[3];
        }
      }
    }
    __syncthreads();                                      // barrier C
    if (wid == 0) {
      float s = (lds.red[0][lane] + lds.red[1][lane]) +
                (lds.red[2][lane] + lds.red[3][lane]);
      lds.lrow[lane] = lds.lrow[lane] * lds.fac[lane] + s;
    }

    // ================= PV: P in regs, V direct from global V^T =================
    bf16x8 pa[4][2];
#pragma unroll
    for (int qt = 0; qt < 4; ++qt) {
      const int base = (16 * qt + l15) * 128;
      pa[qt][0] = *(const bf16x8*)(lds.pl + base + ((16 * h) ^ psw));
      pa[qt][1] = *(const bf16x8*)(lds.pl + base + ((64 + 16 * h) ^ psw));
    }
    const uint16_t* vtW = nullptr;
    if constexpr (USE_VT)
      vtW = vt + ((size_t)(prob * 1024 + 128 * wid + l15)) * 512 + (size_t)kb * 64 + 8 * h;
#pragma unroll
    for (int cd = 0; cd < 8; ++cd) {
      bf16x8 v0, v1;
      if constexpr (USE_VT) {
        const uint16_t* vp = vtW + (size_t)((cd >> 2) * 64 + (cd & 3) * 16) * 512;
        v0 = *(const bf16x8*)(vp);
        v1 = *(const bf16x8*)(vp + 32);
      } else {
        const int d = 128 * wid + (cd >> 2) * 64 + (cd & 3) * 16 + l15;
        union { bf16x8 v; uint16_t u[8]; } a0, a1;
#pragma unroll
        for (int jj = 0; jj < 8; ++jj) {
          int key = kb * 64 + 8 * h + jj;
          a0.u[jj] = (uint16_t)f2bf(xb[(size_t)(gs * 2048 + key * 4 + off) * 1024 + d]);
          a1.u[jj] = (uint16_t)f2bf(xb[(size_t)(gs * 2048 + (key + 32) * 4 + off) * 1024 + d]);
        }
        v0 = a0.v; v1 = a1.v;
      }
#pragma unroll
      for (int qt = 0; qt < 4; ++qt) {
        acc[cd][qt] = __builtin_amdgcn_mfma_f32_16x16x32_bf16(pa[qt][0], v0, acc[cd][qt], 0, 0, 0);
        acc[cd][qt] = __builtin_amdgcn_mfma_f32_16x16x32_bf16(pa[qt][1], v1, acc[cd][qt], 0, 0, 0);
      }
    }
  }

  // ================= epilogue =================
  __syncthreads();   // PV is barrier-free: ensure wid0's last lrow update is visible
#pragma unroll
  for (int qt = 0; qt < 4; ++qt) {
    f32x4 lv = *(const f32x4*)&lds.lrow[16 * qt + 4 * h];
    f32x4 inv;
    inv[0] = 0.25f / lv[0]; inv[1] = 0.25f / lv[1];
    inv[2] = 0.25f / lv[2]; inv[3] = 0.25f / lv[3];
#pragma unroll
    for (int cd = 0; cd < 8; ++cd) {
      const int d = 128 * wid + (cd >> 2) * 64 + (cd & 3) * 16 + l15;
#pragma unroll
      for (int r = 0; r < 4; ++r) {
        const int qq = q0 + 16 * qt + 4 * h + r;
        out[((size_t)(b * 8192 + gs * 2048 + qq * 4 + off)) * 1024 + d] = acc[cd][qt][r] * inv[r];
      }
    }
  }
}

extern "C" void kernel_launch(void* const* d_in, const int* in_sizes, int n_in,
                              void* d_out, int out_size, void* d_ws, size_t ws_size,
                              hipStream_t stream) {
  const float* x = (const float*)d_in[0];
  float* out = (float*)d_out;
  (void)in_sizes; (void)n_in; (void)out_size;
  const size_t vt_bytes = 64ull * 1024 * 512 * 2;   // 67,108,864
  if (ws_size >= vt_bytes) {
    uint16_t* vt = (uint16_t*)d_ws;
    vt_prepass<<<8192, 256, 0, stream>>>(x, vt);
    dilattn_kernel<1><<<512, 512, 0, stream>>>(x, vt, out);
  } else {
    dilattn_kernel<0><<<512, 512, 0, stream>>>(x, nullptr, out);
  }
}

// Round 4
// 308.639 us; speedup vs baseline: 2.3348x; 1.0092x over previous
//
#include <hip/hip_runtime.h>
#include <stdint.h>

typedef __bf16 bf16x8  __attribute__((ext_vector_type(8)));
typedef float  f32x4   __attribute__((ext_vector_type(4)));

#define LOG2E    1.44269504088896340736f
#define SM_SCALE 0.03125f   /* 1/sqrt(1024) */

__device__ __forceinline__ uint32_t f2bf(float f) {
  uint32_t u = __builtin_bit_cast(uint32_t, f);
  u += 0x7FFFu + ((u >> 16) & 1u);   // RNE
  return u >> 16;
}
__device__ __forceinline__ uint32_t pk2(float a, float b) {
  return f2bf(a) | (f2bf(b) << 16);
}
__device__ __forceinline__ uint4 pack8(float4 a, float4 b) {
  uint4 r;
  r.x = pk2(a.x, a.y); r.y = pk2(a.z, a.w);
  r.z = pk2(b.x, b.y); r.w = pk2(b.z, b.w);
  return r;
}

// Dynamic LDS layout (73,728 B total, 1 block/CU... 2 if regs allow):
//  [0,      65536): phase1 K chunk [512 rows][128 B bf16], row-XOR-swizzled ^((row&7)<<4)
//                   phase2/3: aliased by P [64 q][1024 B bf16], same XOR family
//  [65536,  73728): phase1 Q chunk [64 rows][128 B], swizzled
//                   phase2: aliased by red0 (f32[8][64]) @65536, red1 @67584
#define KP_OFF 0
#define Q_OFF  65536
#define RED0   65536
#define RED1   67584
#define LDS_BYTES 73728

// ---------------- prepass: build V^T bf16 [prob][1024 d][512 key] in ws (verified r3) ----------------
__global__ __launch_bounds__(256)
void vt_prepass(const float* __restrict__ x, uint16_t* __restrict__ vt) {
  __shared__ char tl[64 * 144];
  const int t    = threadIdx.x;
  const int blk  = blockIdx.x;
  const int dc   = blk & 15;          // 64-d chunk
  const int kb   = (blk >> 4) & 7;    // 64-key chunk
  const int prob = blk >> 7;          // 0..63
  const int b  = prob >> 4, off = (prob >> 2) & 3, gs = prob & 3;

  const int key = t >> 2, dq = t & 3;
  const float* src = x + ((size_t)(b * 8192 + gs * 2048 + (kb * 64 + key) * 4 + off)) * 1024
                     + dc * 64 + dq * 16;
  float4 f0 = *(const float4*)(src);
  float4 f1 = *(const float4*)(src + 4);
  float4 f2 = *(const float4*)(src + 8);
  float4 f3 = *(const float4*)(src + 12);
  const int swz = (key & 7) << 4;
  *(uint4*)(tl + key * 144 + ((dq * 32) ^ swz))      = pack8(f0, f1);
  *(uint4*)(tl + key * 144 + ((dq * 32 + 16) ^ swz)) = pack8(f2, f3);
  __syncthreads();
  const int d = t >> 2, kq = t & 3;
  uint32_t w[8];
#pragma unroll
  for (int i = 0; i < 8; ++i) {
    int k0 = kq * 16 + 2 * i, k1 = k0 + 1;
    uint32_t a  = *(const uint16_t*)(tl + k0 * 144 + ((2 * d) ^ ((k0 & 7) << 4)));
    uint32_t bb = *(const uint16_t*)(tl + k1 * 144 + ((2 * d) ^ ((k1 & 7) << 4)));
    w[i] = a | (bb << 16);
  }
  uint16_t* dst = vt + ((size_t)(prob * 1024 + dc * 64 + d)) * 512 + kb * 64 + kq * 16;
  *(uint4*)(dst)     = *(uint4*)&w[0];
  *(uint4*)(dst + 8) = *(uint4*)&w[4];
}

// ---------------- main kernel: S-resident (non-flash) ----------------
template <int USE_VT>
__global__ __launch_bounds__(512, 2)
void dilattn2(const float* __restrict__ x, const uint16_t* __restrict__ vt,
              float* __restrict__ out) {
  extern __shared__ char smem[];

  const int tid  = threadIdx.x;
  const int lane = tid & 63;
  const int wid  = tid >> 6;
  const int h    = lane >> 4;        // 0..3
  const int l15  = lane & 15;
  const int psw  = (l15 & 7) << 4;

  const int blk  = blockIdx.x;
  const int prob = blk >> 3;
  const int q0   = (blk & 7) * 64;
  const int b    = prob >> 4;
  const int off  = (prob >> 2) & 3;
  const int gs   = prob & 3;

  const float* xb = x + (size_t)b * (8192u * 1024u);

  // staging coords: 8 threads/row, each 16-B bf16 granule (8 d = 2 float4 fp32)
  const int srow = tid >> 3;         // 0..63
  const int sg   = tid & 7;          // granule
  const float* gK = xb + (size_t)(gs * 2048 + srow * 4 + off) * 1024 + sg * 8;  // + j*262144 for rows srow+64j
  const float* gQ = xb + (size_t)(gs * 2048 + (q0 + srow) * 4 + off) * 1024 + sg * 8;
  const int kWr = srow * 128 + ((sg * 16) ^ ((srow & 7) << 4));   // + j*8192
  const int qWr = Q_OFF + kWr;   // same formula for rows 0..63

  // fragment read bases (verified layout family: row(l15)*stride + (64s+16h)^psw)
  const int akR = (64 * wid + l15) * 128;     // K rows for wave's 64-key strip, + kt*2048
  const int bqR = Q_OFF + l15 * 128;          // Q rows, + qt*2048
  const int fb0 = (16 * h) ^ psw;             // s=0 byte; s=1: fb0 ^ 64

  // S strip: S[key = 64*wid + 16*kt + 4*h + reg][q = q0 + 16*qt + l15]
  f32x4 S[4][4];
#pragma unroll
  for (int i = 0; i < 4; ++i)
#pragma unroll
    for (int j = 0; j < 4; ++j) S[i][j] = (f32x4){0.f, 0.f, 0.f, 0.f};

  // ===== phase 1: S = K Q^T, 16 chunks of 64 d =====
  float4 kp[16], qp[2];
#pragma unroll
  for (int j = 0; j < 8; ++j) {
    const float* p = gK + (size_t)j * 262144;
    kp[2 * j]     = *(const float4*)(p);
    kp[2 * j + 1] = *(const float4*)(p + 4);
  }
  qp[0] = *(const float4*)(gQ);
  qp[1] = *(const float4*)(gQ + 4);

#pragma unroll 1
  for (int dc = 0; dc < 16; ++dc) {
#pragma unroll
    for (int j = 0; j < 8; ++j)
      *(uint4*)(smem + KP_OFF + kWr + j * 8192) = pack8(kp[2 * j], kp[2 * j + 1]);
    *(uint4*)(smem + qWr) = pack8(qp[0], qp[1]);
    if (dc < 15) {                       // T14: issue next chunk's loads before barrier
      const int doff = (dc + 1) * 64;
#pragma unroll
      for (int j = 0; j < 8; ++j) {
        const float* p = gK + (size_t)j * 262144 + doff;
        kp[2 * j]     = *(const float4*)(p);
        kp[2 * j + 1] = *(const float4*)(p + 4);
      }
      qp[0] = *(const float4*)(gQ + doff);
      qp[1] = *(const float4*)(gQ + doff + 4);
    }
    __syncthreads();                     // chunk dc staged
#pragma unroll
    for (int s = 0; s < 2; ++s) {
      const int fb = fb0 ^ (s << 6);
      bf16x8 aK[4], bq[4];
#pragma unroll
      for (int kt = 0; kt < 4; ++kt)
        aK[kt] = *(const bf16x8*)(smem + akR + kt * 2048 + fb);
#pragma unroll
      for (int qt = 0; qt < 4; ++qt)
        bq[qt] = *(const bf16x8*)(smem + bqR + qt * 2048 + fb);
#pragma unroll
      for (int kt = 0; kt < 4; ++kt)
#pragma unroll
        for (int qt = 0; qt < 4; ++qt)
          S[kt][qt] = __builtin_amdgcn_mfma_f32_16x16x32_bf16(aK[kt], bq[qt], S[kt][qt], 0, 0, 0);
    }
    __syncthreads();                     // done reading before next overwrite
  }

  // ===== phase 2: exact softmax (keys 0..511 per q) =====
  float mq[4], sq[4], rinv[4];
#pragma unroll
  for (int qt = 0; qt < 4; ++qt) {
    float m = S[0][qt][0];
#pragma unroll
    for (int kt = 0; kt < 4; ++kt)
#pragma unroll
      for (int r = 0; r < 4; ++r) m = fmaxf(m, S[kt][qt][r]);
    m = fmaxf(m, __shfl_xor(m, 16, 64));
    m = fmaxf(m, __shfl_xor(m, 32, 64));
    mq[qt] = m;
  }
  if (h == 0) {
#pragma unroll
    for (int qt = 0; qt < 4; ++qt)
      *(float*)(smem + RED0 + (wid * 64 + 16 * qt + l15) * 4) = mq[qt];
  }
  __syncthreads();                       // B1: wave maxes visible
#pragma unroll
  for (int qt = 0; qt < 4; ++qt) {
    float m = -3e38f;
#pragma unroll
    for (int w = 0; w < 8; ++w)
      m = fmaxf(m, *(const float*)(smem + RED0 + (w * 64 + 16 * qt + l15) * 4));
    mq[qt] = m * SM_SCALE;
    sq[qt] = 0.f;
  }
#pragma unroll
  for (int kt = 0; kt < 4; ++kt)
#pragma unroll
    for (int qt = 0; qt < 4; ++qt)
#pragma unroll
      for (int r = 0; r < 4; ++r) {
        float v = exp2f((S[kt][qt][r] * SM_SCALE - mq[qt]) * LOG2E);
        S[kt][qt][r] = v;
        sq[qt] += v;
      }
#pragma unroll
  for (int qt = 0; qt < 4; ++qt) {
    sq[qt] += __shfl_xor(sq[qt], 16, 64);
    sq[qt] += __shfl_xor(sq[qt], 32, 64);
  }
  if (h == 0) {
#pragma unroll
    for (int qt = 0; qt < 4; ++qt)
      *(float*)(smem + RED1 + (wid * 64 + 16 * qt + l15) * 4) = sq[qt];
  }
  __syncthreads();                       // B2: wave sums visible
#pragma unroll
  for (int qt = 0; qt < 4; ++qt) {
    float l = 0.f;
#pragma unroll
    for (int w = 0; w < 8; ++w)
      l += *(const float*)(smem + RED1 + (w * 64 + 16 * qt + l15) * 4);
    rinv[qt] = 0.25f / l;                // fold softmax denom AND the /r=4 into P
  }
  // store P (normalized) into KP region: row q (1024 B), byte (2*key) ^ psw
#pragma unroll
  for (int kt = 0; kt < 4; ++kt)
#pragma unroll
    for (int qt = 0; qt < 4; ++qt) {
      uint2 w2;
      w2.x = pk2(S[kt][qt][0] * rinv[qt], S[kt][qt][1] * rinv[qt]);
      w2.y = pk2(S[kt][qt][2] * rinv[qt], S[kt][qt][3] * rinv[qt]);
      *(uint2*)(smem + KP_OFF + (16 * qt + l15) * 1024 +
                ((128 * wid + 32 * kt + 8 * h) ^ psw)) = w2;
    }
  __syncthreads();                       // B3: P ready

  // ===== phase 3: O = P V, barrier-free; wave owns d-slice [128*wid, +128) =====
  f32x4 acc[8][4];
#pragma unroll
  for (int i = 0; i < 8; ++i)
#pragma unroll
    for (int j = 0; j < 4; ++j) acc[i][j] = (f32x4){0.f, 0.f, 0.f, 0.f};

  const uint16_t* vtW = nullptr;
  if constexpr (USE_VT)
    vtW = vt + ((size_t)(prob * 1024 + 128 * wid + l15)) * 512 + 8 * h;

#pragma unroll 1
  for (int ks = 0; ks < 16; ++ks) {
    bf16x8 pa[4];
#pragma unroll
    for (int qt = 0; qt < 4; ++qt)
      pa[qt] = *(const bf16x8*)(smem + KP_OFF + (16 * qt + l15) * 1024 +
                                ((64 * ks + 16 * h) ^ psw));
#pragma unroll
    for (int cd = 0; cd < 8; ++cd) {
      bf16x8 v;
      if constexpr (USE_VT) {
        v = *(const bf16x8*)(vtW + (size_t)((cd >> 2) * 64 + (cd & 3) * 16) * 512 + 32 * ks);
      } else {
        const int d = 128 * wid + (cd >> 2) * 64 + (cd & 3) * 16 + l15;
        union { bf16x8 v; uint16_t u[8]; } a0;
#pragma unroll
        for (int jj = 0; jj < 8; ++jj) {
          int key = 32 * ks + 8 * h + jj;
          a0.u[jj] = (uint16_t)f2bf(xb[(size_t)(gs * 2048 + key * 4 + off) * 1024 + d]);
        }
        v = a0.v;
      }
#pragma unroll
      for (int qt = 0; qt < 4; ++qt)
        acc[cd][qt] = __builtin_amdgcn_mfma_f32_16x16x32_bf16(pa[qt], v, acc[cd][qt], 0, 0, 0);
    }
  }

  // ===== epilogue: store (0.25/l already folded into P) =====
#pragma unroll
  for (int cd = 0; cd < 8; ++cd) {
    const int d = 128 * wid + (cd >> 2) * 64 + (cd & 3) * 16 + l15;
#pragma unroll
    for (int qt = 0; qt < 4; ++qt)
#pragma unroll
      for (int r = 0; r < 4; ++r) {
        const int qq = q0 + 16 * qt + 4 * h + r;
        out[((size_t)(b * 8192 + gs * 2048 + qq * 4 + off)) * 1024 + d] = acc[cd][qt][r];
      }
  }
}

extern "C" void kernel_launch(void* const* d_in, const int* in_sizes, int n_in,
                              void* d_out, int out_size, void* d_ws, size_t ws_size,
                              hipStream_t stream) {
  const float* x = (const float*)d_in[0];
  float* out = (float*)d_out;
  (void)in_sizes; (void)n_in; (void)out_size;
  const size_t vt_bytes = 64ull * 1024 * 512 * 2;   // 64 MiB
  if (ws_size >= vt_bytes) {
    uint16_t* vtp = (uint16_t*)d_ws;
    hipFuncSetAttribute(reinterpret_cast<const void*>(dilattn2<1>),
                        hipFuncAttributeMaxDynamicSharedMemorySize, LDS_BYTES);
    vt_prepass<<<8192, 256, 0, stream>>>(x, vtp);
    dilattn2<1><<<512, 512, LDS_BYTES, stream>>>(x, vtp, out);
  } else {
    hipFuncSetAttribute(reinterpret_cast<const void*>(dilattn2<0>),
                        hipFuncAttributeMaxDynamicSharedMemorySize, LDS_BYTES);
    dilattn2<0><<<512, 512, LDS_BYTES, stream>>>(x, nullptr, out);
  }
}

// Round 5
// 190.680 us; speedup vs baseline: 3.7792x; 1.6186x over previous
//
#include <hip/hip_runtime.h>
#include <stdint.h>

typedef __bf16 bf16x8  __attribute__((ext_vector_type(8)));
typedef float  f32x4   __attribute__((ext_vector_type(4)));

#define LOG2E    1.44269504088896340736f
#define SM_SCALE 0.03125f   /* 1/sqrt(1024) */

typedef __attribute__((address_space(1))) const uint32_t gau32;
typedef __attribute__((address_space(3))) uint32_t       lau32;
#define GLD16(g, l) __builtin_amdgcn_global_load_lds((gau32*)(g), (lau32*)(l), 16, 0, 0)

__device__ __forceinline__ uint32_t f2bf(float f) {
  uint32_t u = __builtin_bit_cast(uint32_t, f);
  u += 0x7FFFu + ((u >> 16) & 1u);   // RNE
  return u >> 16;
}
__device__ __forceinline__ uint32_t pk2(float a, float b) {
  return f2bf(a) | (f2bf(b) << 16);
}
__device__ __forceinline__ uint4 pack8(float4 a, float4 b) {
  uint4 r;
  r.x = pk2(a.x, a.y); r.y = pk2(a.z, a.w);
  r.z = pk2(b.x, b.y); r.w = pk2(b.z, b.w);
  return r;
}

// ================= combined prepass =================
// Writes: vt  [prob][1024 d][512 key]  bf16   (verified r3/r4)
//         xs  [prob][512 row][16 chunk][128B] bf16, granule-swizzled content:
//             xs[r][dc][p*16..] = x granules (p ^ (r&7)) of row r, chunk dc
__global__ __launch_bounds__(256)
void prep_comb(const float* __restrict__ x, uint16_t* __restrict__ vt,
               uint16_t* __restrict__ xs) {
  __shared__ char tl[64 * 144];
  const int t    = threadIdx.x;
  const int blk  = blockIdx.x;
  const int dc   = blk & 15;          // 64-d chunk
  const int kb   = (blk >> 4) & 7;    // 64-key chunk
  const int prob = blk >> 7;          // 0..63
  const int b  = prob >> 4, off = (prob >> 2) & 3, gs = prob & 3;

  const int key = t >> 2, dq = t & 3;
  const float* src = x + ((size_t)(b * 8192 + gs * 2048 + (kb * 64 + key) * 4 + off)) * 1024
                     + dc * 64 + dq * 16;
  float4 f0 = *(const float4*)(src);
  float4 f1 = *(const float4*)(src + 4);
  float4 f2 = *(const float4*)(src + 8);
  float4 f3 = *(const float4*)(src + 12);
  const int swz = (key & 7) << 4;
  *(uint4*)(tl + key * 144 + ((dq * 32) ^ swz))      = pack8(f0, f1);
  *(uint4*)(tl + key * 144 + ((dq * 32 + 16) ^ swz)) = pack8(f2, f3);
  __syncthreads();
  // vt (transposed) — unchanged verified code
  {
    const int d = t >> 2, kq = t & 3;
    uint32_t w[8];
#pragma unroll
    for (int i = 0; i < 8; ++i) {
      int k0 = kq * 16 + 2 * i, k1 = k0 + 1;
      uint32_t a  = *(const uint16_t*)(tl + k0 * 144 + ((2 * d) ^ ((k0 & 7) << 4)));
      uint32_t bb = *(const uint16_t*)(tl + k1 * 144 + ((2 * d) ^ ((k1 & 7) << 4)));
      w[i] = a | (bb << 16);
    }
    uint16_t* dst = vt + ((size_t)(prob * 1024 + dc * 64 + d)) * 512 + kb * 64 + kq * 16;
    *(uint4*)(dst)     = *(uint4*)&w[0];
    *(uint4*)(dst + 8) = *(uint4*)&w[4];
  }
  // xs (row-major, pre-swizzled): tl byte p*16 already holds granule p^(row&7)
  {
    const int row = t >> 2, j = t & 3;
    uint4 w0 = *(const uint4*)(tl + row * 144 + j * 32);
    uint4 w1 = *(const uint4*)(tl + row * 144 + j * 32 + 16);
    char* dst = (char*)xs +
        ((size_t)((prob * 512 + kb * 64 + row) * 16 + dc)) * 128 + j * 32;
    *(uint4*)(dst)      = w0;
    *(uint4*)(dst + 16) = w1;
  }
}

// ================= main kernel v3: bf16 source + global_load_lds =================
// LDS: two 73,728-B buffers: [K 64KB][Q 8KB][pad]; P aliases buf0 K; red aliases buf0 Q
#define B3_STRIDE 73728
#define B3_QOFF   65536
#define R3_0      65536
#define R3_1      67584
#define LDS3_BYTES 147456

__global__ __launch_bounds__(512, 2)
void dilattn3(const uint16_t* __restrict__ xs, const uint16_t* __restrict__ vt,
              float* __restrict__ out) {
  extern __shared__ char smem[];

  const int tid  = threadIdx.x;
  const int lane = tid & 63;
  const int wid  = tid >> 6;
  const int h    = lane >> 4;
  const int l15  = lane & 15;
  const int psw  = (l15 & 7) << 4;

  // XCD-friendly bijection (grid=512): xcd-class = blk&7 gets probs (blk&7)*8..+7
  const int blk  = blockIdx.x;
  const int prob = ((blk & 7) << 3) | (blk >> 6);
  const int q0   = ((blk >> 3) & 7) * 64;
  const int b    = prob >> 4;
  const int off  = (prob >> 2) & 3;
  const int gs   = prob & 3;

  const char* xp = (const char*)xs + (size_t)prob * 1048576;   // 512*16*128

  // staging: per lane, row r8 = lane>>3 within wave's 8-row strip, granule g8
  const int r8 = lane >> 3, g8 = lane & 7;
  const char* gK = xp + (size_t)(wid * 8 + r8) * 2048 + g8 * 16;        // + i*131072 + dc*128
  const char* gQ = xp + (size_t)(q0 + wid * 8 + r8) * 2048 + g8 * 16;   // + dc*128

  // fragment read bases (content model identical to verified r4 layout)
  const int akR = (64 * wid + l15) * 128;
  const int bqR = B3_QOFF + l15 * 128;
  const int fb0 = (16 * h) ^ psw;

  f32x4 S[4][4];
#pragma unroll
  for (int i = 0; i < 4; ++i)
#pragma unroll
    for (int j = 0; j < 4; ++j) S[i][j] = (f32x4){0.f, 0.f, 0.f, 0.f};

  // ===== phase 1: S = K Q^T over 16 d-chunks, LDS-dbuf via global_load_lds =====
  {
    // prologue: stage chunk 0 -> buf0
    {
      char* base = smem;
#pragma unroll
      for (int ii = 0; ii < 8; ++ii)
        GLD16(gK + ii * 131072, base + wid * 1024 + ii * 8192);
      GLD16(gQ, base + B3_QOFF + wid * 1024);
    }
    __syncthreads();
#pragma unroll 1
    for (int dc = 0; dc < 16; ++dc) {
      if (dc < 15) {                       // stage next chunk into other buffer
        char* nb = smem + ((dc + 1) & 1) * B3_STRIDE;
        const int go = (dc + 1) * 128;
#pragma unroll
        for (int ii = 0; ii < 8; ++ii)
          GLD16(gK + ii * 131072 + go, nb + wid * 1024 + ii * 8192);
        GLD16(gQ + go, nb + B3_QOFF + wid * 1024);
      }
      const char* base = smem + (dc & 1) * B3_STRIDE;
#pragma unroll
      for (int s = 0; s < 2; ++s) {
        const int fb = fb0 ^ (s << 6);
        bf16x8 aK[4], bq[4];
#pragma unroll
        for (int kt = 0; kt < 4; ++kt)
          aK[kt] = *(const bf16x8*)(base + akR + kt * 2048 + fb);
#pragma unroll
        for (int qt = 0; qt < 4; ++qt)
          bq[qt] = *(const bf16x8*)(base + bqR + qt * 2048 + fb);
#pragma unroll
        for (int kt = 0; kt < 4; ++kt)
#pragma unroll
          for (int qt = 0; qt < 4; ++qt)
            S[kt][qt] = __builtin_amdgcn_mfma_f32_16x16x32_bf16(aK[kt], bq[qt], S[kt][qt], 0, 0, 0);
      }
      __syncthreads();   // drains vmcnt(0)+lgkmcnt(0): next-chunk DMA landed, reads done
    }
  }

  // ===== phase 2: exact softmax =====
  float mq[4], sq[4], rinv[4];
#pragma unroll
  for (int qt = 0; qt < 4; ++qt) {
    float m = S[0][qt][0];
#pragma unroll
    for (int kt = 0; kt < 4; ++kt)
#pragma unroll
      for (int r = 0; r < 4; ++r) m = fmaxf(m, S[kt][qt][r]);
    m = fmaxf(m, __shfl_xor(m, 16, 64));
    m = fmaxf(m, __shfl_xor(m, 32, 64));
    mq[qt] = m;
  }
  if (h == 0) {
#pragma unroll
    for (int qt = 0; qt < 4; ++qt)
      *(float*)(smem + R3_0 + (wid * 64 + 16 * qt + l15) * 4) = mq[qt];
  }
  __syncthreads();
#pragma unroll
  for (int qt = 0; qt < 4; ++qt) {
    float m = -3e38f;
#pragma unroll
    for (int w = 0; w < 8; ++w)
      m = fmaxf(m, *(const float*)(smem + R3_0 + (w * 64 + 16 * qt + l15) * 4));
    mq[qt] = m * SM_SCALE;
    sq[qt] = 0.f;
  }
#pragma unroll
  for (int kt = 0; kt < 4; ++kt)
#pragma unroll
    for (int qt = 0; qt < 4; ++qt)
#pragma unroll
      for (int r = 0; r < 4; ++r) {
        float v = exp2f((S[kt][qt][r] * SM_SCALE - mq[qt]) * LOG2E);
        S[kt][qt][r] = v;
        sq[qt] += v;
      }
#pragma unroll
  for (int qt = 0; qt < 4; ++qt) {
    sq[qt] += __shfl_xor(sq[qt], 16, 64);
    sq[qt] += __shfl_xor(sq[qt], 32, 64);
  }
  if (h == 0) {
#pragma unroll
    for (int qt = 0; qt < 4; ++qt)
      *(float*)(smem + R3_1 + (wid * 64 + 16 * qt + l15) * 4) = sq[qt];
  }
  __syncthreads();
#pragma unroll
  for (int qt = 0; qt < 4; ++qt) {
    float l = 0.f;
#pragma unroll
    for (int w = 0; w < 8; ++w)
      l += *(const float*)(smem + R3_1 + (w * 64 + 16 * qt + l15) * 4);
    rinv[qt] = 0.25f / l;               // fold denom and /r=4 into P
  }
#pragma unroll
  for (int kt = 0; kt < 4; ++kt)
#pragma unroll
    for (int qt = 0; qt < 4; ++qt) {
      uint2 w2;
      w2.x = pk2(S[kt][qt][0] * rinv[qt], S[kt][qt][1] * rinv[qt]);
      w2.y = pk2(S[kt][qt][2] * rinv[qt], S[kt][qt][3] * rinv[qt]);
      *(uint2*)(smem + (16 * qt + l15) * 1024 +
                ((128 * wid + 32 * kt + 8 * h) ^ psw)) = w2;
    }
  __syncthreads();                       // P ready

  // ===== phase 3: O = P V from global V^T (1-deep prefetch), barrier-free =====
  f32x4 acc[8][4];
#pragma unroll
  for (int i = 0; i < 8; ++i)
#pragma unroll
    for (int j = 0; j < 4; ++j) acc[i][j] = (f32x4){0.f, 0.f, 0.f, 0.f};

  const char* vtW = (const char*)(vt + ((size_t)(prob * 1024 + 128 * wid + l15)) * 512 + 8 * h);
  bf16x8 vcur[8], vnxt[8];
#pragma unroll
  for (int cd = 0; cd < 8; ++cd)
    vcur[cd] = *(const bf16x8*)(vtW + ((cd >> 2) * 64 + (cd & 3) * 16) * 1024);
#pragma unroll 1
  for (int ks = 0; ks < 16; ++ks) {
    if (ks < 15) {
#pragma unroll
      for (int cd = 0; cd < 8; ++cd)
        vnxt[cd] = *(const bf16x8*)(vtW + ((cd >> 2) * 64 + (cd & 3) * 16) * 1024 + (ks + 1) * 64);
    }
    bf16x8 pa[4];
#pragma unroll
    for (int qt = 0; qt < 4; ++qt)
      pa[qt] = *(const bf16x8*)(smem + (16 * qt + l15) * 1024 + ((64 * ks + 16 * h) ^ psw));
#pragma unroll
    for (int cd = 0; cd < 8; ++cd)
#pragma unroll
      for (int qt = 0; qt < 4; ++qt)
        acc[cd][qt] = __builtin_amdgcn_mfma_f32_16x16x32_bf16(pa[qt], vcur[cd], acc[cd][qt], 0, 0, 0);
#pragma unroll
    for (int cd = 0; cd < 8; ++cd) vcur[cd] = vnxt[cd];
  }

  // ===== epilogue =====
#pragma unroll
  for (int cd = 0; cd < 8; ++cd) {
    const int d = 128 * wid + (cd >> 2) * 64 + (cd & 3) * 16 + l15;
#pragma unroll
    for (int qt = 0; qt < 4; ++qt)
#pragma unroll
      for (int r = 0; r < 4; ++r) {
        const int qq = q0 + 16 * qt + 4 * h + r;
        out[((size_t)(b * 8192 + gs * 2048 + qq * 4 + off)) * 1024 + d] = acc[cd][qt][r];
      }
  }
}

// ======================================================================
// ============ fallback path (round-4, verified PASS) ==================
#define KP_OFF 0
#define Q_OFF  65536
#define RED0   65536
#define RED1   67584
#define LDS_BYTES 73728

__global__ __launch_bounds__(256)
void vt_prepass(const float* __restrict__ x, uint16_t* __restrict__ vt) {
  __shared__ char tl[64 * 144];
  const int t    = threadIdx.x;
  const int blk  = blockIdx.x;
  const int dc   = blk & 15;
  const int kb   = (blk >> 4) & 7;
  const int prob = blk >> 7;
  const int b  = prob >> 4, off = (prob >> 2) & 3, gs = prob & 3;

  const int key = t >> 2, dq = t & 3;
  const float* src = x + ((size_t)(b * 8192 + gs * 2048 + (kb * 64 + key) * 4 + off)) * 1024
                     + dc * 64 + dq * 16;
  float4 f0 = *(const float4*)(src);
  float4 f1 = *(const float4*)(src + 4);
  float4 f2 = *(const float4*)(src + 8);
  float4 f3 = *(const float4*)(src + 12);
  const int swz = (key & 7) << 4;
  *(uint4*)(tl + key * 144 + ((dq * 32) ^ swz))      = pack8(f0, f1);
  *(uint4*)(tl + key * 144 + ((dq * 32 + 16) ^ swz)) = pack8(f2, f3);
  __syncthreads();
  const int d = t >> 2, kq = t & 3;
  uint32_t w[8];
#pragma unroll
  for (int i = 0; i < 8; ++i) {
    int k0 = kq * 16 + 2 * i, k1 = k0 + 1;
    uint32_t a  = *(const uint16_t*)(tl + k0 * 144 + ((2 * d) ^ ((k0 & 7) << 4)));
    uint32_t bb = *(const uint16_t*)(tl + k1 * 144 + ((2 * d) ^ ((k1 & 7) << 4)));
    w[i] = a | (bb << 16);
  }
  uint16_t* dst = vt + ((size_t)(prob * 1024 + dc * 64 + d)) * 512 + kb * 64 + kq * 16;
  *(uint4*)(dst)     = *(uint4*)&w[0];
  *(uint4*)(dst + 8) = *(uint4*)&w[4];
}

template <int USE_VT>
__global__ __launch_bounds__(512, 2)
void dilattn2(const float* __restrict__ x, const uint16_t* __restrict__ vt,
              float* __restrict__ out) {
  extern __shared__ char smem[];

  const int tid  = threadIdx.x;
  const int lane = tid & 63;
  const int wid  = tid >> 6;
  const int h    = lane >> 4;
  const int l15  = lane & 15;
  const int psw  = (l15 & 7) << 4;

  const int blk  = blockIdx.x;
  const int prob = blk >> 3;
  const int q0   = (blk & 7) * 64;
  const int b    = prob >> 4;
  const int off  = (prob >> 2) & 3;
  const int gs   = prob & 3;

  const float* xb = x + (size_t)b * (8192u * 1024u);

  const int srow = tid >> 3;
  const int sg   = tid & 7;
  const float* gK = xb + (size_t)(gs * 2048 + srow * 4 + off) * 1024 + sg * 8;
  const float* gQ = xb + (size_t)(gs * 2048 + (q0 + srow) * 4 + off) * 1024 + sg * 8;
  const int kWr = srow * 128 + ((sg * 16) ^ ((srow & 7) << 4));
  const int qWr = Q_OFF + kWr;

  const int akR = (64 * wid + l15) * 128;
  const int bqR = Q_OFF + l15 * 128;
  const int fb0 = (16 * h) ^ psw;

  f32x4 S[4][4];
#pragma unroll
  for (int i = 0; i < 4; ++i)
#pragma unroll
    for (int j = 0; j < 4; ++j) S[i][j] = (f32x4){0.f, 0.f, 0.f, 0.f};

  float4 kp[16], qp[2];
#pragma unroll
  for (int j = 0; j < 8; ++j) {
    const float* p = gK + (size_t)j * 262144;
    kp[2 * j]     = *(const float4*)(p);
    kp[2 * j + 1] = *(const float4*)(p + 4);
  }
  qp[0] = *(const float4*)(gQ);
  qp[1] = *(const float4*)(gQ + 4);

#pragma unroll 1
  for (int dc = 0; dc < 16; ++dc) {
#pragma unroll
    for (int j = 0; j < 8; ++j)
      *(uint4*)(smem + KP_OFF + kWr + j * 8192) = pack8(kp[2 * j], kp[2 * j + 1]);
    *(uint4*)(smem + qWr) = pack8(qp[0], qp[1]);
    if (dc < 15) {
      const int doff = (dc + 1) * 64;
#pragma unroll
      for (int j = 0; j < 8; ++j) {
        const float* p = gK + (size_t)j * 262144 + doff;
        kp[2 * j]     = *(const float4*)(p);
        kp[2 * j + 1] = *(const float4*)(p + 4);
      }
      qp[0] = *(const float4*)(gQ + doff);
      qp[1] = *(const float4*)(gQ + doff + 4);
    }
    __syncthreads();
#pragma unroll
    for (int s = 0; s < 2; ++s) {
      const int fb = fb0 ^ (s << 6);
      bf16x8 aK[4], bq[4];
#pragma unroll
      for (int kt = 0; kt < 4; ++kt)
        aK[kt] = *(const bf16x8*)(smem + akR + kt * 2048 + fb);
#pragma unroll
      for (int qt = 0; qt < 4; ++qt)
        bq[qt] = *(const bf16x8*)(smem + bqR + qt * 2048 + fb);
#pragma unroll
      for (int kt = 0; kt < 4; ++kt)
#pragma unroll
        for (int qt = 0; qt < 4; ++qt)
          S[kt][qt] = __builtin_amdgcn_mfma_f32_16x16x32_bf16(aK[kt], bq[qt], S[kt][qt], 0, 0, 0);
    }
    __syncthreads();
  }

  float mq[4], sq[4], rinv[4];
#pragma unroll
  for (int qt = 0; qt < 4; ++qt) {
    float m = S[0][qt][0];
#pragma unroll
    for (int kt = 0; kt < 4; ++kt)
#pragma unroll
      for (int r = 0; r < 4; ++r) m = fmaxf(m, S[kt][qt][r]);
    m = fmaxf(m, __shfl_xor(m, 16, 64));
    m = fmaxf(m, __shfl_xor(m, 32, 64));
    mq[qt] = m;
  }
  if (h == 0) {
#pragma unroll
    for (int qt = 0; qt < 4; ++qt)
      *(float*)(smem + RED0 + (wid * 64 + 16 * qt + l15) * 4) = mq[qt];
  }
  __syncthreads();
#pragma unroll
  for (int qt = 0; qt < 4; ++qt) {
    float m = -3e38f;
#pragma unroll
    for (int w = 0; w < 8; ++w)
      m = fmaxf(m, *(const float*)(smem + RED0 + (w * 64 + 16 * qt + l15) * 4));
    mq[qt] = m * SM_SCALE;
    sq[qt] = 0.f;
  }
#pragma unroll
  for (int kt = 0; kt < 4; ++kt)
#pragma unroll
    for (int qt = 0; qt < 4; ++qt)
#pragma unroll
      for (int r = 0; r < 4; ++r) {
        float v = exp2f((S[kt][qt][r] * SM_SCALE - mq[qt]) * LOG2E);
        S[kt][qt][r] = v;
        sq[qt] += v;
      }
#pragma unroll
  for (int qt = 0; qt < 4; ++qt) {
    sq[qt] += __shfl_xor(sq[qt], 16, 64);
    sq[qt] += __shfl_xor(sq[qt], 32, 64);
  }
  if (h == 0) {
#pragma unroll
    for (int qt = 0; qt < 4; ++qt)
      *(float*)(smem + RED1 + (wid * 64 + 16 * qt + l15) * 4) = sq[qt];
  }
  __syncthreads();
#pragma unroll
  for (int qt = 0; qt < 4; ++qt) {
    float l = 0.f;
#pragma unroll
    for (int w = 0; w < 8; ++w)
      l += *(const float*)(smem + RED1 + (w * 64 + 16 * qt + l15) * 4);
    rinv[qt] = 0.25f / l;
  }
#pragma unroll
  for (int kt = 0; kt < 4; ++kt)
#pragma unroll
    for (int qt = 0; qt < 4; ++qt) {
      uint2 w2;
      w2.x = pk2(S[kt][qt][0] * rinv[qt], S[kt][qt][1] * rinv[qt]);
      w2.y = pk2(S[kt][qt][2] * rinv[qt], S[kt][qt][3] * rinv[qt]);
      *(uint2*)(smem + KP_OFF + (16 * qt + l15) * 1024 +
                ((128 * wid + 32 * kt + 8 * h) ^ psw)) = w2;
    }
  __syncthreads();

  f32x4 acc[8][4];
#pragma unroll
  for (int i = 0; i < 8; ++i)
#pragma unroll
    for (int j = 0; j < 4; ++j) acc[i][j] = (f32x4){0.f, 0.f, 0.f, 0.f};

  const uint16_t* vtW = nullptr;
  if constexpr (USE_VT)
    vtW = vt + ((size_t)(prob * 1024 + 128 * wid + l15)) * 512 + 8 * h;

#pragma unroll 1
  for (int ks = 0; ks < 16; ++ks) {
    bf16x8 pa[4];
#pragma unroll
    for (int qt = 0; qt < 4; ++qt)
      pa[qt] = *(const bf16x8*)(smem + KP_OFF + (16 * qt + l15) * 1024 +
                                ((64 * ks + 16 * h) ^ psw));
#pragma unroll
    for (int cd = 0; cd < 8; ++cd) {
      bf16x8 v;
      if constexpr (USE_VT) {
        v = *(const bf16x8*)(vtW + (size_t)((cd >> 2) * 64 + (cd & 3) * 16) * 512 + 32 * ks);
      } else {
        const int d = 128 * wid + (cd >> 2) * 64 + (cd & 3) * 16 + l15;
        union { bf16x8 v; uint16_t u[8]; } a0;
#pragma unroll
        for (int jj = 0; jj < 8; ++jj) {
          int key = 32 * ks + 8 * h + jj;
          a0.u[jj] = (uint16_t)f2bf(xb[(size_t)(gs * 2048 + key * 4 + off) * 1024 + d]);
        }
        v = a0.v;
      }
#pragma unroll
      for (int qt = 0; qt < 4; ++qt)
        acc[cd][qt] = __builtin_amdgcn_mfma_f32_16x16x32_bf16(pa[qt], v, acc[cd][qt], 0, 0, 0);
    }
  }

#pragma unroll
  for (int cd = 0; cd < 8; ++cd) {
    const int d = 128 * wid + (cd >> 2) * 64 + (cd & 3) * 16 + l15;
#pragma unroll
    for (int qt = 0; qt < 4; ++qt)
#pragma unroll
      for (int r = 0; r < 4; ++r) {
        const int qq = q0 + 16 * qt + 4 * h + r;
        out[((size_t)(b * 8192 + gs * 2048 + qq * 4 + off)) * 1024 + d] = acc[cd][qt][r];
      }
  }
}

extern "C" void kernel_launch(void* const* d_in, const int* in_sizes, int n_in,
                              void* d_out, int out_size, void* d_ws, size_t ws_size,
                              hipStream_t stream) {
  const float* x = (const float*)d_in[0];
  float* out = (float*)d_out;
  (void)in_sizes; (void)n_in; (void)out_size;
  const size_t vt_bytes = 64ull * 1024 * 512 * 2;   // 64 MiB
  const size_t xs_bytes = 64ull * 512 * 16 * 128;   // 64 MiB
  if (ws_size >= vt_bytes + xs_bytes) {
    uint16_t* vtp = (uint16_t*)d_ws;
    uint16_t* xsp = (uint16_t*)((char*)d_ws + vt_bytes);
    hipFuncSetAttribute(reinterpret_cast<const void*>(dilattn3),
                        hipFuncAttributeMaxDynamicSharedMemorySize, LDS3_BYTES);
    prep_comb<<<8192, 256, 0, stream>>>(x, vtp, xsp);
    dilattn3<<<512, 512, LDS3_BYTES, stream>>>(xsp, vtp, out);
  } else if (ws_size >= vt_bytes) {
    uint16_t* vtp = (uint16_t*)d_ws;
    hipFuncSetAttribute(reinterpret_cast<const void*>(dilattn2<1>),
                        hipFuncAttributeMaxDynamicSharedMemorySize, LDS_BYTES);
    vt_prepass<<<8192, 256, 0, stream>>>(x, vtp);
    dilattn2<1><<<512, 512, LDS_BYTES, stream>>>(x, vtp, out);
  } else {
    hipFuncSetAttribute(reinterpret_cast<const void*>(dilattn2<0>),
                        hipFuncAttributeMaxDynamicSharedMemorySize, LDS_BYTES);
    dilattn2<0><<<512, 512, LDS_BYTES, stream>>>(x, nullptr, out);
  }
}

// Round 6
// 182.696 us; speedup vs baseline: 3.9443x; 1.0437x over previous
//
#include <hip/hip_runtime.h>
#include <stdint.h>

typedef __bf16 bf16x8  __attribute__((ext_vector_type(8)));
typedef float  f32x4   __attribute__((ext_vector_type(4)));

#define LOG2E    1.44269504088896340736f
#define SM_SCALE 0.03125f   /* 1/sqrt(1024) */

typedef __attribute__((address_space(1))) const uint32_t gau32;
typedef __attribute__((address_space(3))) uint32_t       lau32;
#define GLD16(g, l) __builtin_amdgcn_global_load_lds((gau32*)(g), (lau32*)(l), 16, 0, 0)

// barrier that drains LDS ops only (lets global loads stay in flight)
#define LGKM_BAR() do { asm volatile("s_waitcnt lgkmcnt(0)" ::: "memory"); \
  __builtin_amdgcn_s_barrier(); asm volatile("" ::: "memory"); } while (0)

__device__ __forceinline__ uint32_t f2bf(float f) {
  uint32_t u = __builtin_bit_cast(uint32_t, f);
  u += 0x7FFFu + ((u >> 16) & 1u);   // RNE
  return u >> 16;
}
__device__ __forceinline__ uint32_t pk2(float a, float b) {
  return f2bf(a) | (f2bf(b) << 16);
}
__device__ __forceinline__ uint4 pack8(float4 a, float4 b) {
  uint4 r;
  r.x = pk2(a.x, a.y); r.y = pk2(a.z, a.w);
  r.z = pk2(b.x, b.y); r.w = pk2(b.z, b.w);
  return r;
}

// ================= combined prepass (verified r5; at HBM roofline) =================
__global__ __launch_bounds__(256)
void prep_comb(const float* __restrict__ x, uint16_t* __restrict__ vt,
               uint16_t* __restrict__ xs) {
  __shared__ char tl[64 * 144];
  const int t    = threadIdx.x;
  const int blk  = blockIdx.x;
  const int dc   = blk & 15;          // 64-d chunk
  const int kb   = (blk >> 4) & 7;    // 64-key chunk
  const int prob = blk >> 7;          // 0..63
  const int b  = prob >> 4, off = (prob >> 2) & 3, gs = prob & 3;

  const int key = t >> 2, dq = t & 3;
  const float* src = x + ((size_t)(b * 8192 + gs * 2048 + (kb * 64 + key) * 4 + off)) * 1024
                     + dc * 64 + dq * 16;
  float4 f0 = *(const float4*)(src);
  float4 f1 = *(const float4*)(src + 4);
  float4 f2 = *(const float4*)(src + 8);
  float4 f3 = *(const float4*)(src + 12);
  const int swz = (key & 7) << 4;
  *(uint4*)(tl + key * 144 + ((dq * 32) ^ swz))      = pack8(f0, f1);
  *(uint4*)(tl + key * 144 + ((dq * 32 + 16) ^ swz)) = pack8(f2, f3);
  __syncthreads();
  // vt (transposed)
  {
    const int d = t >> 2, kq = t & 3;
    uint32_t w[8];
#pragma unroll
    for (int i = 0; i < 8; ++i) {
      int k0 = kq * 16 + 2 * i, k1 = k0 + 1;
      uint32_t a  = *(const uint16_t*)(tl + k0 * 144 + ((2 * d) ^ ((k0 & 7) << 4)));
      uint32_t bb = *(const uint16_t*)(tl + k1 * 144 + ((2 * d) ^ ((k1 & 7) << 4)));
      w[i] = a | (bb << 16);
    }
    uint16_t* dst = vt + ((size_t)(prob * 1024 + dc * 64 + d)) * 512 + kb * 64 + kq * 16;
    *(uint4*)(dst)     = *(uint4*)&w[0];
    *(uint4*)(dst + 8) = *(uint4*)&w[4];
  }
  // xs (row-major, pre-swizzled)
  {
    const int row = t >> 2, j = t & 3;
    uint4 w0 = *(const uint4*)(tl + row * 144 + j * 32);
    uint4 w1 = *(const uint4*)(tl + row * 144 + j * 32 + 16);
    char* dst = (char*)xs +
        ((size_t)((prob * 512 + kb * 64 + row) * 16 + dc)) * 128 + j * 32;
    *(uint4*)(dst)      = w0;
    *(uint4*)(dst + 16) = w1;
  }
}

// ================= main kernel v4: counted-wait schedule =================
#define B3_STRIDE 73728
#define B3_QOFF   65536
#define R3_0      65536
#define R3_1      67584
#define LDS3_BYTES 147456

__global__ __launch_bounds__(512, 2)
void dilattn3(const uint16_t* __restrict__ xs, const uint16_t* __restrict__ vt,
              float* __restrict__ out) {
  extern __shared__ char smem[];

  const int tid  = threadIdx.x;
  const int lane = tid & 63;
  const int wid  = tid >> 6;
  const int h    = lane >> 4;
  const int l15  = lane & 15;
  const int psw  = (l15 & 7) << 4;

  const int blk  = blockIdx.x;
  const int prob = ((blk & 7) << 3) | (blk >> 6);
  const int q0   = ((blk >> 3) & 7) * 64;
  const int b    = prob >> 4;
  const int off  = (prob >> 2) & 3;
  const int gs   = prob & 3;

  const char* xp = (const char*)xs + (size_t)prob * 1048576;

  const int r8 = lane >> 3, g8 = lane & 7;
  const char* gK = xp + (size_t)(wid * 8 + r8) * 2048 + g8 * 16;
  const char* gQ = xp + (size_t)(q0 + wid * 8 + r8) * 2048 + g8 * 16;

  const int akR = (64 * wid + l15) * 128;
  const int bqR = B3_QOFF + l15 * 128;
  const int fb0 = (16 * h) ^ psw;

  f32x4 S[4][4];
#pragma unroll
  for (int i = 0; i < 4; ++i)
#pragma unroll
    for (int j = 0; j < 4; ++j) S[i][j] = (f32x4){0.f, 0.f, 0.f, 0.f};

  // ===== phase 1: S = K Q^T over 16 d-chunks =====
  // schedule per chunk: [wait own batch c (issued 1 interval ago)] [barrier]
  //                     [issue batch c+1] [16 ds_reads + 32 MFMA]
  {
    char* base0 = smem;
#pragma unroll
    for (int ii = 0; ii < 8; ++ii)
      GLD16(gK + ii * 131072, base0 + wid * 1024 + ii * 8192);
    GLD16(gQ, base0 + B3_QOFF + wid * 1024);
  }
#pragma unroll 1
  for (int dc = 0; dc < 16; ++dc) {
    asm volatile("s_waitcnt vmcnt(0)" ::: "memory");   // batch dc landed (all 9)
    __builtin_amdgcn_s_barrier();                      // all waves' batch dc + prev reads done
    asm volatile("" ::: "memory");
    if (dc < 15) {                                     // overwrite buffer read 2 barriers ago
      char* nb = smem + ((dc + 1) & 1) * B3_STRIDE;
      const int go = (dc + 1) * 128;
#pragma unroll
      for (int ii = 0; ii < 8; ++ii)
        GLD16(gK + ii * 131072 + go, nb + wid * 1024 + ii * 8192);
      GLD16(gQ + go, nb + B3_QOFF + wid * 1024);
    }
    const char* base = smem + (dc & 1) * B3_STRIDE;
    bf16x8 aK[8], bq[8];
#pragma unroll
    for (int s = 0; s < 2; ++s) {
      const int fb = fb0 ^ (s << 6);
#pragma unroll
      for (int kt = 0; kt < 4; ++kt)
        aK[s * 4 + kt] = *(const bf16x8*)(base + akR + kt * 2048 + fb);
#pragma unroll
      for (int qt = 0; qt < 4; ++qt)
        bq[s * 4 + qt] = *(const bf16x8*)(base + bqR + qt * 2048 + fb);
    }
    __builtin_amdgcn_s_setprio(1);
#pragma unroll
    for (int s = 0; s < 2; ++s)
#pragma unroll
      for (int kt = 0; kt < 4; ++kt)
#pragma unroll
        for (int qt = 0; qt < 4; ++qt)
          S[kt][qt] = __builtin_amdgcn_mfma_f32_16x16x32_bf16(aK[s * 4 + kt], bq[s * 4 + qt],
                                                              S[kt][qt], 0, 0, 0);
    __builtin_amdgcn_s_setprio(0);
  }

  // ===== phase-3 V prologue hoisted: loads ride through phase-2 lgkm barriers =====
  const char* vtW = (const char*)(vt + ((size_t)(prob * 1024 + 128 * wid + l15)) * 512 + 8 * h);
  bf16x8 vA[8], vB[8];
#pragma unroll
  for (int cd = 0; cd < 8; ++cd) {
    vA[cd] = *(const bf16x8*)(vtW + ((cd >> 2) * 64 + (cd & 3) * 16) * 1024);
    vB[cd] = *(const bf16x8*)(vtW + ((cd >> 2) * 64 + (cd & 3) * 16) * 1024 + 64);
  }

  // ===== phase 2: exact softmax (lgkm-only barriers) =====
  float mq[4], sq[4], rinv[4];
#pragma unroll
  for (int qt = 0; qt < 4; ++qt) {
    float m = S[0][qt][0];
#pragma unroll
    for (int kt = 0; kt < 4; ++kt)
#pragma unroll
      for (int r = 0; r < 4; ++r) m = fmaxf(m, S[kt][qt][r]);
    m = fmaxf(m, __shfl_xor(m, 16, 64));
    m = fmaxf(m, __shfl_xor(m, 32, 64));
    mq[qt] = m;
  }
  if (h == 0) {
#pragma unroll
    for (int qt = 0; qt < 4; ++qt)
      *(float*)(smem + R3_0 + (wid * 64 + 16 * qt + l15) * 4) = mq[qt];
  }
  LGKM_BAR();                            // B1
#pragma unroll
  for (int qt = 0; qt < 4; ++qt) {
    float m = -3e38f;
#pragma unroll
    for (int w = 0; w < 8; ++w)
      m = fmaxf(m, *(const float*)(smem + R3_0 + (w * 64 + 16 * qt + l15) * 4));
    mq[qt] = m * SM_SCALE;
    sq[qt] = 0.f;
  }
#pragma unroll
  for (int kt = 0; kt < 4; ++kt)
#pragma unroll
    for (int qt = 0; qt < 4; ++qt)
#pragma unroll
      for (int r = 0; r < 4; ++r) {
        float v = exp2f((S[kt][qt][r] * SM_SCALE - mq[qt]) * LOG2E);
        S[kt][qt][r] = v;
        sq[qt] += v;
      }
#pragma unroll
  for (int qt = 0; qt < 4; ++qt) {
    sq[qt] += __shfl_xor(sq[qt], 16, 64);
    sq[qt] += __shfl_xor(sq[qt], 32, 64);
  }
  if (h == 0) {
#pragma unroll
    for (int qt = 0; qt < 4; ++qt)
      *(float*)(smem + R3_1 + (wid * 64 + 16 * qt + l15) * 4) = sq[qt];
  }
  LGKM_BAR();                            // B2
#pragma unroll
  for (int qt = 0; qt < 4; ++qt) {
    float l = 0.f;
#pragma unroll
    for (int w = 0; w < 8; ++w)
      l += *(const float*)(smem + R3_1 + (w * 64 + 16 * qt + l15) * 4);
    rinv[qt] = 0.25f / l;               // fold denom and /r=4 into P
  }
#pragma unroll
  for (int kt = 0; kt < 4; ++kt)
#pragma unroll
    for (int qt = 0; qt < 4; ++qt) {
      uint2 w2;
      w2.x = pk2(S[kt][qt][0] * rinv[qt], S[kt][qt][1] * rinv[qt]);
      w2.y = pk2(S[kt][qt][2] * rinv[qt], S[kt][qt][3] * rinv[qt]);
      *(uint2*)(smem + (16 * qt + l15) * 1024 +
                ((128 * wid + 32 * kt + 8 * h) ^ psw)) = w2;
    }
  LGKM_BAR();                            // B3: P ready

  // ===== phase 3: O = P V, depth-2 register pipeline, barrier-free =====
  f32x4 acc[8][4];
#pragma unroll
  for (int i = 0; i < 8; ++i)
#pragma unroll
    for (int j = 0; j < 4; ++j) acc[i][j] = (f32x4){0.f, 0.f, 0.f, 0.f};

#pragma unroll 1
  for (int ks = 0; ks < 16; ks += 2) {
    {
      bf16x8 pa[4];
#pragma unroll
      for (int qt = 0; qt < 4; ++qt)
        pa[qt] = *(const bf16x8*)(smem + (16 * qt + l15) * 1024 + ((64 * ks + 16 * h) ^ psw));
      __builtin_amdgcn_s_setprio(1);
#pragma unroll
      for (int cd = 0; cd < 8; ++cd)
#pragma unroll
        for (int qt = 0; qt < 4; ++qt)
          acc[cd][qt] = __builtin_amdgcn_mfma_f32_16x16x32_bf16(pa[qt], vA[cd], acc[cd][qt], 0, 0, 0);
      __builtin_amdgcn_s_setprio(0);
      if (ks + 2 < 16) {
#pragma unroll
        for (int cd = 0; cd < 8; ++cd)
          vA[cd] = *(const bf16x8*)(vtW + ((cd >> 2) * 64 + (cd & 3) * 16) * 1024 + (ks + 2) * 64);
      }
    }
    {
      bf16x8 pa[4];
#pragma unroll
      for (int qt = 0; qt < 4; ++qt)
        pa[qt] = *(const bf16x8*)(smem + (16 * qt + l15) * 1024 + ((64 * (ks + 1) + 16 * h) ^ psw));
      __builtin_amdgcn_s_setprio(1);
#pragma unroll
      for (int cd = 0; cd < 8; ++cd)
#pragma unroll
        for (int qt = 0; qt < 4; ++qt)
          acc[cd][qt] = __builtin_amdgcn_mfma_f32_16x16x32_bf16(pa[qt], vB[cd], acc[cd][qt], 0, 0, 0);
      __builtin_amdgcn_s_setprio(0);
      if (ks + 3 < 16) {
#pragma unroll
        for (int cd = 0; cd < 8; ++cd)
          vB[cd] = *(const bf16x8*)(vtW + ((cd >> 2) * 64 + (cd & 3) * 16) * 1024 + (ks + 3) * 64);
      }
    }
  }

  // ===== epilogue =====
#pragma unroll
  for (int cd = 0; cd < 8; ++cd) {
    const int d = 128 * wid + (cd >> 2) * 64 + (cd & 3) * 16 + l15;
#pragma unroll
    for (int qt = 0; qt < 4; ++qt)
#pragma unroll
      for (int r = 0; r < 4; ++r) {
        const int qq = q0 + 16 * qt + 4 * h + r;
        out[((size_t)(b * 8192 + gs * 2048 + qq * 4 + off)) * 1024 + d] = acc[cd][qt][r];
      }
  }
}

// ======================================================================
// ============ fallback path (round-4, verified PASS) ==================
#define KP_OFF 0
#define Q_OFF  65536
#define RED0   65536
#define RED1   67584
#define LDS_BYTES 73728

__global__ __launch_bounds__(256)
void vt_prepass(const float* __restrict__ x, uint16_t* __restrict__ vt) {
  __shared__ char tl[64 * 144];
  const int t    = threadIdx.x;
  const int blk  = blockIdx.x;
  const int dc   = blk & 15;
  const int kb   = (blk >> 4) & 7;
  const int prob = blk >> 7;
  const int b  = prob >> 4, off = (prob >> 2) & 3, gs = prob & 3;

  const int key = t >> 2, dq = t & 3;
  const float* src = x + ((size_t)(b * 8192 + gs * 2048 + (kb * 64 + key) * 4 + off)) * 1024
                     + dc * 64 + dq * 16;
  float4 f0 = *(const float4*)(src);
  float4 f1 = *(const float4*)(src + 4);
  float4 f2 = *(const float4*)(src + 8);
  float4 f3 = *(const float4*)(src + 12);
  const int swz = (key & 7) << 4;
  *(uint4*)(tl + key * 144 + ((dq * 32) ^ swz))      = pack8(f0, f1);
  *(uint4*)(tl + key * 144 + ((dq * 32 + 16) ^ swz)) = pack8(f2, f3);
  __syncthreads();
  const int d = t >> 2, kq = t & 3;
  uint32_t w[8];
#pragma unroll
  for (int i = 0; i < 8; ++i) {
    int k0 = kq * 16 + 2 * i, k1 = k0 + 1;
    uint32_t a  = *(const uint16_t*)(tl + k0 * 144 + ((2 * d) ^ ((k0 & 7) << 4)));
    uint32_t bb = *(const uint16_t*)(tl + k1 * 144 + ((2 * d) ^ ((k1 & 7) << 4)));
    w[i] = a | (bb << 16);
  }
  uint16_t* dst = vt + ((size_t)(prob * 1024 + dc * 64 + d)) * 512 + kb * 64 + kq * 16;
  *(uint4*)(dst)     = *(uint4*)&w[0];
  *(uint4*)(dst + 8) = *(uint4*)&w[4];
}

template <int USE_VT>
__global__ __launch_bounds__(512, 2)
void dilattn2(const float* __restrict__ x, const uint16_t* __restrict__ vt,
              float* __restrict__ out) {
  extern __shared__ char smem[];

  const int tid  = threadIdx.x;
  const int lane = tid & 63;
  const int wid  = tid >> 6;
  const int h    = lane >> 4;
  const int l15  = lane & 15;
  const int psw  = (l15 & 7) << 4;

  const int blk  = blockIdx.x;
  const int prob = blk >> 3;
  const int q0   = (blk & 7) * 64;
  const int b    = prob >> 4;
  const int off  = (prob >> 2) & 3;
  const int gs   = prob & 3;

  const float* xb = x + (size_t)b * (8192u * 1024u);

  const int srow = tid >> 3;
  const int sg   = tid & 7;
  const float* gK = xb + (size_t)(gs * 2048 + srow * 4 + off) * 1024 + sg * 8;
  const float* gQ = xb + (size_t)(gs * 2048 + (q0 + srow) * 4 + off) * 1024 + sg * 8;
  const int kWr = srow * 128 + ((sg * 16) ^ ((srow & 7) << 4));
  const int qWr = Q_OFF + kWr;

  const int akR = (64 * wid + l15) * 128;
  const int bqR = Q_OFF + l15 * 128;
  const int fb0 = (16 * h) ^ psw;

  f32x4 S[4][4];
#pragma unroll
  for (int i = 0; i < 4; ++i)
#pragma unroll
    for (int j = 0; j < 4; ++j) S[i][j] = (f32x4){0.f, 0.f, 0.f, 0.f};

  float4 kp[16], qp[2];
#pragma unroll
  for (int j = 0; j < 8; ++j) {
    const float* p = gK + (size_t)j * 262144;
    kp[2 * j]     = *(const float4*)(p);
    kp[2 * j + 1] = *(const float4*)(p + 4);
  }
  qp[0] = *(const float4*)(gQ);
  qp[1] = *(const float4*)(gQ + 4);

#pragma unroll 1
  for (int dc = 0; dc < 16; ++dc) {
#pragma unroll
    for (int j = 0; j < 8; ++j)
      *(uint4*)(smem + KP_OFF + kWr + j * 8192) = pack8(kp[2 * j], kp[2 * j + 1]);
    *(uint4*)(smem + qWr) = pack8(qp[0], qp[1]);
    if (dc < 15) {
      const int doff = (dc + 1) * 64;
#pragma unroll
      for (int j = 0; j < 8; ++j) {
        const float* p = gK + (size_t)j * 262144 + doff;
        kp[2 * j]     = *(const float4*)(p);
        kp[2 * j + 1] = *(const float4*)(p + 4);
      }
      qp[0] = *(const float4*)(gQ + doff);
      qp[1] = *(const float4*)(gQ + doff + 4);
    }
    __syncthreads();
#pragma unroll
    for (int s = 0; s < 2; ++s) {
      const int fb = fb0 ^ (s << 6);
      bf16x8 aK[4], bq[4];
#pragma unroll
      for (int kt = 0; kt < 4; ++kt)
        aK[kt] = *(const bf16x8*)(smem + akR + kt * 2048 + fb);
#pragma unroll
      for (int qt = 0; qt < 4; ++qt)
        bq[qt] = *(const bf16x8*)(smem + bqR + qt * 2048 + fb);
#pragma unroll
      for (int kt = 0; kt < 4; ++kt)
#pragma unroll
        for (int qt = 0; qt < 4; ++qt)
          S[kt][qt] = __builtin_amdgcn_mfma_f32_16x16x32_bf16(aK[kt], bq[qt], S[kt][qt], 0, 0, 0);
    }
    __syncthreads();
  }

  float mq[4], sq[4], rinv[4];
#pragma unroll
  for (int qt = 0; qt < 4; ++qt) {
    float m = S[0][qt][0];
#pragma unroll
    for (int kt = 0; kt < 4; ++kt)
#pragma unroll
      for (int r = 0; r < 4; ++r) m = fmaxf(m, S[kt][qt][r]);
    m = fmaxf(m, __shfl_xor(m, 16, 64));
    m = fmaxf(m, __shfl_xor(m, 32, 64));
    mq[qt] = m;
  }
  if (h == 0) {
#pragma unroll
    for (int qt = 0; qt < 4; ++qt)
      *(float*)(smem + RED0 + (wid * 64 + 16 * qt + l15) * 4) = mq[qt];
  }
  __syncthreads();
#pragma unroll
  for (int qt = 0; qt < 4; ++qt) {
    float m = -3e38f;
#pragma unroll
    for (int w = 0; w < 8; ++w)
      m = fmaxf(m, *(const float*)(smem + RED0 + (w * 64 + 16 * qt + l15) * 4));
    mq[qt] = m * SM_SCALE;
    sq[qt] = 0.f;
  }
#pragma unroll
  for (int kt = 0; kt < 4; ++kt)
#pragma unroll
    for (int qt = 0; qt < 4; ++qt)
#pragma unroll
      for (int r = 0; r < 4; ++r) {
        float v = exp2f((S[kt][qt][r] * SM_SCALE - mq[qt]) * LOG2E);
        S[kt][qt][r] = v;
        sq[qt] += v;
      }
#pragma unroll
  for (int qt = 0; qt < 4; ++qt) {
    sq[qt] += __shfl_xor(sq[qt], 16, 64);
    sq[qt] += __shfl_xor(sq[qt], 32, 64);
  }
  if (h == 0) {
#pragma unroll
    for (int qt = 0; qt < 4; ++qt)
      *(float*)(smem + RED1 + (wid * 64 + 16 * qt + l15) * 4) = sq[qt];
  }
  __syncthreads();
#pragma unroll
  for (int qt = 0; qt < 4; ++qt) {
    float l = 0.f;
#pragma unroll
    for (int w = 0; w < 8; ++w)
      l += *(const float*)(smem + RED1 + (w * 64 + 16 * qt + l15) * 4);
    rinv[qt] = 0.25f / l;
  }
#pragma unroll
  for (int kt = 0; kt < 4; ++kt)
#pragma unroll
    for (int qt = 0; qt < 4; ++qt) {
      uint2 w2;
      w2.x = pk2(S[kt][qt][0] * rinv[qt], S[kt][qt][1] * rinv[qt]);
      w2.y = pk2(S[kt][qt][2] * rinv[qt], S[kt][qt][3] * rinv[qt]);
      *(uint2*)(smem + KP_OFF + (16 * qt + l15) * 1024 +
                ((128 * wid + 32 * kt + 8 * h) ^ psw)) = w2;
    }
  __syncthreads();

  f32x4 acc[8][4];
#pragma unroll
  for (int i = 0; i < 8; ++i)
#pragma unroll
    for (int j = 0; j < 4; ++j) acc[i][j] = (f32x4){0.f, 0.f, 0.f, 0.f};

  const uint16_t* vtW = nullptr;
  if constexpr (USE_VT)
    vtW = vt + ((size_t)(prob * 1024 + 128 * wid + l15)) * 512 + 8 * h;

#pragma unroll 1
  for (int ks = 0; ks < 16; ++ks) {
    bf16x8 pa[4];
#pragma unroll
    for (int qt = 0; qt < 4; ++qt)
      pa[qt] = *(const bf16x8*)(smem + KP_OFF + (16 * qt + l15) * 1024 +
                                ((64 * ks + 16 * h) ^ psw));
#pragma unroll
    for (int cd = 0; cd < 8; ++cd) {
      bf16x8 v;
      if constexpr (USE_VT) {
        v = *(const bf16x8*)(vtW + (size_t)((cd >> 2) * 64 + (cd & 3) * 16) * 512 + 32 * ks);
      } else {
        const int d = 128 * wid + (cd >> 2) * 64 + (cd & 3) * 16 + l15;
        union { bf16x8 v; uint16_t u[8]; } a0;
#pragma unroll
        for (int jj = 0; jj < 8; ++jj) {
          int key = 32 * ks + 8 * h + jj;
          a0.u[jj] = (uint16_t)f2bf(xb[(size_t)(gs * 2048 + key * 4 + off) * 1024 + d]);
        }
        v = a0.v;
      }
#pragma unroll
      for (int qt = 0; qt < 4; ++qt)
        acc[cd][qt] = __builtin_amdgcn_mfma_f32_16x16x32_bf16(pa[qt], v, acc[cd][qt], 0, 0, 0);
    }
  }

#pragma unroll
  for (int cd = 0; cd < 8; ++cd) {
    const int d = 128 * wid + (cd >> 2) * 64 + (cd & 3) * 16 + l15;
#pragma unroll
    for (int qt = 0; qt < 4; ++qt)
#pragma unroll
      for (int r = 0; r < 4; ++r) {
        const int qq = q0 + 16 * qt + 4 * h + r;
        out[((size_t)(b * 8192 + gs * 2048 + qq * 4 + off)) * 1024 + d] = acc[cd][qt][r];
      }
  }
}

extern "C" void kernel_launch(void* const* d_in, const int* in_sizes, int n_in,
                              void* d_out, int out_size, void* d_ws, size_t ws_size,
                              hipStream_t stream) {
  const float* x = (const float*)d_in[0];
  float* out = (float*)d_out;
  (void)in_sizes; (void)n_in; (void)out_size;
  const size_t vt_bytes = 64ull * 1024 * 512 * 2;   // 64 MiB
  const size_t xs_bytes = 64ull * 512 * 16 * 128;   // 64 MiB
  if (ws_size >= vt_bytes + xs_bytes) {
    uint16_t* vtp = (uint16_t*)d_ws;
    uint16_t* xsp = (uint16_t*)((char*)d_ws + vt_bytes);
    hipFuncSetAttribute(reinterpret_cast<const void*>(dilattn3),
                        hipFuncAttributeMaxDynamicSharedMemorySize, LDS3_BYTES);
    prep_comb<<<8192, 256, 0, stream>>>(x, vtp, xsp);
    dilattn3<<<512, 512, LDS3_BYTES, stream>>>(xsp, vtp, out);
  } else if (ws_size >= vt_bytes) {
    uint16_t* vtp = (uint16_t*)d_ws;
    hipFuncSetAttribute(reinterpret_cast<const void*>(dilattn2<1>),
                        hipFuncAttributeMaxDynamicSharedMemorySize, LDS_BYTES);
    vt_prepass<<<8192, 256, 0, stream>>>(x, vtp);
    dilattn2<1><<<512, 512, LDS_BYTES, stream>>>(x, vtp, out);
  } else {
    hipFuncSetAttribute(reinterpret_cast<const void*>(dilattn2<0>),
                        hipFuncAttributeMaxDynamicSharedMemorySize, LDS_BYTES);
    dilattn2<0><<<512, 512, LDS_BYTES, stream>>>(x, nullptr, out);
  }
}